// Round 1
// baseline (91.827 us; speedup 1.0000x reference)
//
#include <hip/hip_runtime.h>
#include <hip/hip_bf16.h>

typedef unsigned short u16;
typedef __bf16 bf16;
typedef bf16 bf16x8 __attribute__((ext_vector_type(8)));
typedef float f32x4 __attribute__((ext_vector_type(4)));

#define B_ 8
#define T_ 2048
#define C_ 768
#define H_ 64
#define M_ (B_*T_)
#define QK_BYTES (M_*H_*2)        // 2 MiB per bf16 [16384][64] matrix
#define WT_STEP_BYTES (192*128)   // one K-step image of Wt
#define LOG2E 1.4426950408889634f

#define AS1 __attribute__((address_space(1)))
#define AS3 __attribute__((address_space(3)))

__device__ __forceinline__ void g2l16(const void* g, void* l) {
  __builtin_amdgcn_global_load_lds((AS1 const void*)g, (AS3 void*)l, 16, 0, 0);
}

__device__ __forceinline__ u16 bf2u(bf16 h) {
  union { bf16 h; u16 u; } x; x.h = h; return x.u;
}

// ---------------------------------------------------------------------------
// Kernel 1: build pre-swizzled Wt image: per K-step s (24), rows j=0..191
// (0..63 = Wq cols, 64..127 = Wk, 128..191 = Wv), 128B pitch,
// element (j, kk) at byte (s*192+j)*128 + ((2*kk) ^ ((j&7)<<4)).
// ---------------------------------------------------------------------------
__global__ __launch_bounds__(256) void prepw_kernel(const float* __restrict__ Wq,
                                                    const float* __restrict__ Wk,
                                                    const float* __restrict__ Wv,
                                                    u16* __restrict__ wt_img) {
  int tid = blockIdx.x * 256 + threadIdx.x;        // 3*768*64 = 147456 exactly
  int jj = tid & 63;
  int k  = (tid >> 6) % C_;
  int m  = tid / (64 * C_);
  const float* W = (m == 0) ? Wq : (m == 1 ? Wk : Wv);
  bf16 hv = (bf16)W[k * 64 + jj];
  int s = k >> 5, kk = k & 31, j = m * 64 + jj;
  int byteoff = (s * 192 + j) * 128 + ((2 * kk) ^ ((j & 7) << 4));
  *(u16*)((char*)wt_img + byteoff) = bf2u(hv);
}

// ---------------------------------------------------------------------------
// Kernel 2: projections. Block = 64 rows x 192 cols, 4 waves, K-loop 24x32.
// ---------------------------------------------------------------------------
__global__ __launch_bounds__(256) void proj_kernel(const float* __restrict__ x,
                                                   const u16* __restrict__ wt_img,
                                                   u16* __restrict__ q_ws,
                                                   u16* __restrict__ k_img,
                                                   u16* __restrict__ v_ws) {
  __shared__ __align__(16) char sA[64 * 128];
  __shared__ __align__(16) char sB[192 * 128];
  int tid = threadIdx.x, lane = tid & 63, w = tid >> 6;
  int r0 = blockIdx.x * 64;

  f32x4 acc[12];
#pragma unroll
  for (int i = 0; i < 12; ++i) acc[i] = (f32x4){0.f, 0.f, 0.f, 0.f};

  int arow = tid >> 2, ac0 = (tid & 3) * 8;
  const float* xp = x + (size_t)(r0 + arow) * C_ + ac0;
  char* aDst = sA + arow * 128 + ((2 * ac0) ^ ((arow & 7) << 4));
  int frow = w * 16 + (lane & 15);
  int kb16 = 16 * (lane >> 4);

  for (int s = 0; s < 24; ++s) {
    // stage A (fp32 -> bf16, swizzled ds_write_b128)
    float4 f0 = *(const float4*)(xp + s * 32);
    float4 f1 = *(const float4*)(xp + s * 32 + 4);
    bf16x8 av;
    av[0] = (bf16)f0.x; av[1] = (bf16)f0.y; av[2] = (bf16)f0.z; av[3] = (bf16)f0.w;
    av[4] = (bf16)f1.x; av[5] = (bf16)f1.y; av[6] = (bf16)f1.z; av[7] = (bf16)f1.w;
    *(bf16x8*)aDst = av;
    // stage B: linear 24KB copy of pre-swizzled image
    const char* wsrc = (const char*)wt_img + s * (24576);
#pragma unroll
    for (int i = 0; i < 6; ++i) {
      int off = (i * 256 + tid) * 16;
      g2l16(wsrc + off, sB + off);
    }
    __syncthreads();

    bf16x8 af = *(const bf16x8*)(sA + frow * 128 + (kb16 ^ ((frow & 7) << 4)));
#pragma unroll
    for (int nt = 0; nt < 12; ++nt) {
      int brow = nt * 16 + (lane & 15);
      bf16x8 bfr = *(const bf16x8*)(sB + brow * 128 + (kb16 ^ ((brow & 7) << 4)));
      acc[nt] = __builtin_amdgcn_mfma_f32_16x16x32_bf16(af, bfr, acc[nt], 0, 0, 0);
    }
    __syncthreads();
  }

  // epilogue: D layout col = lane&15, row = (lane>>4)*4 + reg
  int g = lane >> 4, c = lane & 15;
#pragma unroll
  for (int nt = 0; nt < 12; ++nt) {
    int m = nt >> 2, hb = (nt & 3) * 16;
#pragma unroll
    for (int reg = 0; reg < 4; ++reg) {
      int r = r0 + w * 16 + g * 4 + reg;
      int h = hb + c;
      u16 bits = bf2u((bf16)acc[nt][reg]);
      if (m == 0)      q_ws[r * 64 + h] = bits;
      else if (m == 1) *(u16*)((char*)k_img + r * 128 + ((2 * h) ^ ((r & 7) << 4))) = bits;
      else             v_ws[r * 64 + h] = bits;
    }
  }
}

// ---------------------------------------------------------------------------
// Kernel 3: V transpose into pre-swizzled Vt image [b][h][t] with per-128B
// chunk swizzle: byte = b*256K + h*4096 + (t>>6)*128 + ((2*(t&63)) ^ ((h&7)<<4))
// ---------------------------------------------------------------------------
__global__ __launch_bounds__(256) void vtrans_kernel(const u16* __restrict__ v_ws,
                                                     u16* __restrict__ vt_img) {
  __shared__ u16 tile[64 * 66];   // pitch 66 to dodge bank conflicts
  int b = blockIdx.x >> 5, tt = blockIdx.x & 31;
  int tid = threadIdx.x;
  const u16* src = v_ws + (size_t)(b * T_ + tt * 64) * 64;
#pragma unroll
  for (int i = 0; i < 2; ++i) {
    int idx = tid + i * 256;
    int r = idx >> 3, c0 = (idx & 7) * 8;
    const ushort4* sp = (const ushort4*)(src + r * 64 + c0);
    ushort4 a = sp[0], bq = sp[1];
    ushort2* d = (ushort2*)&tile[r * 66 + c0];
    ushort2 t0; t0.x = a.x;  t0.y = a.y;  d[0] = t0;
    ushort2 t1; t1.x = a.z;  t1.y = a.w;  d[1] = t1;
    ushort2 t2; t2.x = bq.x; t2.y = bq.y; d[2] = t2;
    ushort2 t3; t3.x = bq.z; t3.y = bq.w; d[3] = t3;
  }
  __syncthreads();
  u16* vt = vt_img + (size_t)b * (64 * T_);
#pragma unroll
  for (int i = 0; i < 2; ++i) {
    int idx = tid + i * 256;
    int h = idx >> 3, kv0 = (idx & 7) * 8;
    u16 vals[8];
#pragma unroll
    for (int j = 0; j < 8; ++j) vals[j] = tile[(kv0 + j) * 66 + h];
    u16* dst = vt + h * T_ + tt * 64 + (kv0 ^ ((h & 7) << 3));
    ushort4 o0; o0.x = vals[0]; o0.y = vals[1]; o0.z = vals[2]; o0.w = vals[3];
    ushort4 o1; o1.x = vals[4]; o1.y = vals[5]; o1.z = vals[6]; o1.w = vals[7];
    ((ushort4*)dst)[0] = o0;
    ((ushort4*)dst)[1] = o1;
  }
}

// ---------------------------------------------------------------------------
// Kernel 4: causal flash attention. Block = 32 q-rows (2 waves), KV tiles of 64.
// Grid 512: b = i&7 (one batch per XCD), q-tiles paired x with 63-x per CU.
// ---------------------------------------------------------------------------
__global__ __launch_bounds__(128) void attn_kernel(const u16* __restrict__ q_ws,
                                                   const u16* __restrict__ k_img,
                                                   const u16* __restrict__ vt_img,
                                                   float* __restrict__ out) {
  __shared__ __align__(16) char sK[64 * 128];
  __shared__ __align__(16) char sV[64 * 128];
  __shared__ __align__(16) char sP[2 * 16 * 128];
  int tid = threadIdx.x, lane = tid & 63, w = tid >> 6;
  int i = blockIdx.x;
  int b = i & 7;
  int j = i >> 3;
  int qt = (j < 32) ? j : (95 - j);     // pair heavy with light tiles on a CU
  int q0 = qt * 32;

  int g = lane >> 4, c = lane & 15;
  int kb16 = 16 * g;

  // Q fragments in registers (A-operand: row = lane&15, k = 8*(lane>>4)+j)
  int qrow = q0 + w * 16 + c;
  const u16* qbase = q_ws + (size_t)(b * T_ + qrow) * 64;
  bf16x8 qa0 = *(const bf16x8*)(qbase + 8 * g);
  bf16x8 qa1 = *(const bf16x8*)(qbase + 32 + 8 * g);

  f32x4 accO[4];
#pragma unroll
  for (int n = 0; n < 4; ++n) accO[n] = (f32x4){0.f, 0.f, 0.f, 0.f};
  float m4[4] = {-__builtin_inff(), -__builtin_inff(), -__builtin_inff(), -__builtin_inff()};
  float l4[4] = {0.f, 0.f, 0.f, 0.f};

  int nkt = (q0 >> 6) + 1;
  const char* kbp = (const char*)k_img + (size_t)(b * T_) * 128;
  const char* vbp = (const char*)vt_img + (size_t)b * (64 * T_ * 2);
  char* pbase = sP + w * 2048;

  for (int kt = 0; kt < nkt; ++kt) {
    int kv0 = kt * 64;
    // stage K tile (8KB linear, pre-swizzled source)
    const char* ksrc = kbp + (size_t)kv0 * 128;
#pragma unroll
    for (int ii = 0; ii < 4; ++ii) {
      int off = (ii * 128 + tid) * 16;
      g2l16(ksrc + off, sK + off);
    }
    // stage Vt tile (row h: one 128B chunk per h, pre-swizzled source)
#pragma unroll
    for (int ii = 0; ii < 4; ++ii) {
      int j2 = ii * 128 + tid;
      int h = j2 >> 3, bo = (j2 & 7) * 16;
      g2l16(vbp + (size_t)h * (T_ * 2) + kt * 128 + bo, sV + j2 * 16);
    }
    __syncthreads();

    // S = Q K^T / 8
    f32x4 s4[4];
#pragma unroll
    for (int nt = 0; nt < 4; ++nt) {
      int br = nt * 16 + c;
      int sw = (br & 7) << 4;
      const char* kr = sK + br * 128;
      bf16x8 b0 = *(const bf16x8*)(kr + (kb16 ^ sw));
      bf16x8 b1 = *(const bf16x8*)(kr + ((64 + kb16) ^ sw));
      f32x4 z = (f32x4){0.f, 0.f, 0.f, 0.f};
      f32x4 t = __builtin_amdgcn_mfma_f32_16x16x32_bf16(qa0, b0, z, 0, 0, 0);
      t = __builtin_amdgcn_mfma_f32_16x16x32_bf16(qa1, b1, t, 0, 0, 0);
      s4[nt] = t * 0.125f;
    }
    // causal mask (diagonal tile only)
    if (kt == nkt - 1) {
      int colb = kv0 + c;
      int rowb = q0 + w * 16 + (g << 2);
#pragma unroll
      for (int nt = 0; nt < 4; ++nt)
#pragma unroll
        for (int reg = 0; reg < 4; ++reg)
          if (colb + nt * 16 > rowb + reg) s4[nt][reg] = -__builtin_inff();
    }
    // online softmax (wave-parallel: 16-lane groups hold one row's 64 cols)
#pragma unroll
    for (int reg = 0; reg < 4; ++reg) {
      float smax = fmaxf(fmaxf(s4[0][reg], s4[1][reg]), fmaxf(s4[2][reg], s4[3][reg]));
#pragma unroll
      for (int d = 1; d < 16; d <<= 1) smax = fmaxf(smax, __shfl_xor(smax, d, 16));
      float mnew = fmaxf(m4[reg], smax);
      float sf = exp2f((m4[reg] - mnew) * LOG2E);
      float rsum = 0.f;
#pragma unroll
      for (int nt = 0; nt < 4; ++nt) {
        float p = exp2f((s4[nt][reg] - mnew) * LOG2E);
        s4[nt][reg] = p;
        rsum += p;
      }
#pragma unroll
      for (int d = 1; d < 16; d <<= 1) rsum += __shfl_xor(rsum, d, 16);
      l4[reg] = l4[reg] * sf + rsum;
      m4[reg] = mnew;
#pragma unroll
      for (int nt = 0; nt < 4; ++nt) accO[nt][reg] *= sf;
    }
    // P -> bf16 -> wave-private swizzled LDS tile
#pragma unroll
    for (int reg = 0; reg < 4; ++reg) {
      int ql = g * 4 + reg;
      int swp = (ql & 7) << 4;
#pragma unroll
      for (int nt = 0; nt < 4; ++nt) {
        *(u16*)(pbase + ql * 128 + ((2 * (nt * 16 + c)) ^ swp)) = bf2u((bf16)s4[nt][reg]);
      }
    }
    // O += P V
#pragma unroll
    for (int ks = 0; ks < 2; ++ks) {
      int ql = c;
      bf16x8 pa = *(const bf16x8*)(pbase + ql * 128 + ((ks * 64 + kb16) ^ ((ql & 7) << 4)));
#pragma unroll
      for (int nt = 0; nt < 4; ++nt) {
        int vr = nt * 16 + c;
        bf16x8 vf = *(const bf16x8*)(sV + vr * 128 + ((ks * 64 + kb16) ^ ((vr & 7) << 4)));
        accO[nt] = __builtin_amdgcn_mfma_f32_16x16x32_bf16(pa, vf, accO[nt], 0, 0, 0);
      }
    }
    __syncthreads();
  }

  // epilogue: out = accO / l
  float* ob = out + (size_t)(b * T_) * 64;
#pragma unroll
  for (int nt = 0; nt < 4; ++nt)
#pragma unroll
    for (int reg = 0; reg < 4; ++reg) {
      int r = q0 + w * 16 + g * 4 + reg;
      ob[(size_t)r * 64 + nt * 16 + c] = accO[nt][reg] / l4[reg];
    }
}

// ---------------------------------------------------------------------------
extern "C" void kernel_launch(void* const* d_in, const int* in_sizes, int n_in,
                              void* d_out, int out_size, void* d_ws, size_t ws_size,
                              hipStream_t stream) {
  const float* x  = (const float*)d_in[0];
  const float* Wk = (const float*)d_in[1];
  const float* Wq = (const float*)d_in[2];
  const float* Wv = (const float*)d_in[3];
  char* ws = (char*)d_ws;
  u16* q_ws   = (u16*)(ws + 0);
  u16* k_img  = (u16*)(ws + (size_t)QK_BYTES);
  u16* v_ws   = (u16*)(ws + (size_t)2 * QK_BYTES);
  u16* vt_img = (u16*)(ws + (size_t)3 * QK_BYTES);
  u16* wt_img = (u16*)(ws + (size_t)4 * QK_BYTES);
  float* out = (float*)d_out;

  prepw_kernel<<<576, 256, 0, stream>>>(Wq, Wk, Wv, wt_img);
  proj_kernel<<<256, 256, 0, stream>>>(x, wt_img, q_ws, k_img, v_ws);
  vtrans_kernel<<<256, 256, 0, stream>>>(v_ws, vt_img);
  attn_kernel<<<512, 128, 0, stream>>>(q_ws, k_img, vt_img, out);
}

// Round 2
// 89.585 us; speedup vs baseline: 1.0250x; 1.0250x over previous
//
#include <hip/hip_runtime.h>
#include <hip/hip_bf16.h>

typedef unsigned short u16;
typedef __bf16 bf16;
typedef bf16 bf16x4 __attribute__((ext_vector_type(4)));
typedef bf16 bf16x8 __attribute__((ext_vector_type(8)));
typedef float f32x4 __attribute__((ext_vector_type(4)));

#define B_ 8
#define T_ 2048
#define C_ 768
#define LOG2E 1.4426950408889634f
#define MB 1048576ull

#define AS1 __attribute__((address_space(1)))
#define AS3 __attribute__((address_space(3)))

__device__ __forceinline__ void g2l16(const void* g, void* l) {
  __builtin_amdgcn_global_load_lds((AS1 const void*)g, (AS3 void*)l, 16, 0, 0);
}
__device__ __forceinline__ u16 bf2u(bf16 h) {
  union { bf16 h; u16 u; } x; x.h = h; return x.u;
}

// ---------------------------------------------------------------------------
// Kernel 1: pre-swizzled Wt image: per K-step s (24), rows j=0..191
// (0..63 = Wq cols, 64..127 = Wk, 128..191 = Wv), 128B pitch,
// element (j, kk) at byte (s*192+j)*128 + ((2*kk) ^ ((j&7)<<4)).
// ---------------------------------------------------------------------------
__global__ __launch_bounds__(256) void prepw_kernel(const float* __restrict__ Wq,
                                                    const float* __restrict__ Wk,
                                                    const float* __restrict__ Wv,
                                                    u16* __restrict__ wt_img) {
  int tid = blockIdx.x * 256 + threadIdx.x;        // 3*768*64 = 147456 exactly
  int jj = tid & 63;
  int k  = (tid >> 6) % C_;
  int m  = tid / (64 * C_);
  const float* W = (m == 0) ? Wq : (m == 1 ? Wk : Wv);
  bf16 hv = (bf16)W[k * 64 + jj];
  int s = k >> 5, kk = k & 31, j = m * 64 + jj;
  int byteoff = (s * 192 + j) * 128 + ((2 * kk) ^ ((j & 7) << 4));
  *(u16*)((char*)wt_img + byteoff) = bf2u(hv);
}

// ---------------------------------------------------------------------------
// Kernel 2: projections. Block = 64 rows x 192 cols, 8 waves (4m x 2n),
// K-loop 24x32. q scaled by 0.125 (softmax 1/sqrt(64)), v written transposed.
// ---------------------------------------------------------------------------
__global__ __launch_bounds__(512) void proj_kernel(const float* __restrict__ x,
                                                   const u16* __restrict__ wt_img,
                                                   u16* __restrict__ q_ws,
                                                   u16* __restrict__ k_ws,
                                                   u16* __restrict__ vt_ws) {
  __shared__ __align__(16) char sA[64 * 128];
  __shared__ __align__(16) char sB[192 * 128];
  int tid = threadIdx.x, lane = tid & 63, w = tid >> 6;
  int wm = w & 3, wn = w >> 2;
  int r0 = blockIdx.x * 64;

  f32x4 acc[6];
#pragma unroll
  for (int i = 0; i < 6; ++i) acc[i] = (f32x4){0.f, 0.f, 0.f, 0.f};

  int arow = tid >> 3, ak0 = (tid & 7) * 4;
  const float* xp = x + (size_t)(r0 + arow) * C_ + ak0;
  char* aDst = sA + arow * 128 + ((2 * ak0) ^ ((arow & 7) << 4));
  int c = lane & 15, g = lane >> 4;
  int frow = wm * 16 + c, kb16 = 16 * g;

  for (int s = 0; s < 24; ++s) {
    float4 f0 = *(const float4*)(xp + s * 32);
    bf16x4 av;
    av[0] = (bf16)f0.x; av[1] = (bf16)f0.y; av[2] = (bf16)f0.z; av[3] = (bf16)f0.w;
    *(bf16x4*)aDst = av;
    const char* wsrc = (const char*)wt_img + s * 24576;
#pragma unroll
    for (int i = 0; i < 3; ++i) {
      int off = (i * 512 + tid) * 16;
      g2l16(wsrc + off, sB + off);
    }
    __syncthreads();

    bf16x8 af = *(const bf16x8*)(sA + frow * 128 + (kb16 ^ ((frow & 7) << 4)));
#pragma unroll
    for (int nt = 0; nt < 6; ++nt) {
      int brow = wn * 96 + nt * 16 + c;
      bf16x8 bfr = *(const bf16x8*)(sB + brow * 128 + (kb16 ^ ((brow & 7) << 4)));
      acc[nt] = __builtin_amdgcn_mfma_f32_16x16x32_bf16(af, bfr, acc[nt], 0, 0, 0);
    }
    __syncthreads();
  }

  // epilogue: D layout col = lane&15, row = (lane>>4)*4 + reg
#pragma unroll
  for (int nt = 0; nt < 6; ++nt) {
    int gc = wn * 96 + nt * 16;
    int m = gc >> 6;
    int h = (gc & 63) + c;
#pragma unroll
    for (int reg = 0; reg < 4; ++reg) {
      int r = r0 + wm * 16 + g * 4 + reg;
      float val = acc[nt][reg];
      if (m == 0)      q_ws[(size_t)r * 64 + h] = bf2u((bf16)(val * 0.125f));
      else if (m == 1) k_ws[(size_t)r * 64 + h] = bf2u((bf16)val);
      else             vt_ws[((size_t)(r >> 11) * 64 + h) * T_ + (r & 2047)] = bf2u((bf16)val);
    }
  }
}

// ---------------------------------------------------------------------------
// Kernel 3: causal flash attention, split-KV. 1 wave = 16 q-rows x <=8 KV
// tiles of 64. No barriers: K/Vt fragments load direct global->VGPR;
// P-transpose through wave-private LDS. Partials to ws for multi-chunk rows.
// Waves/batch = 320: qt 0..31 -> 1 chunk, 32..63 -> 2, 64..95 -> 3, 96..127 -> 4.
// ---------------------------------------------------------------------------
__global__ __launch_bounds__(256) void attn_kernel(const u16* __restrict__ q_ws,
                                                   const u16* __restrict__ k_ws,
                                                   const u16* __restrict__ vt_ws,
                                                   float* __restrict__ po,
                                                   float* __restrict__ ml,
                                                   float* __restrict__ out) {
  __shared__ __align__(16) char sP[4 * 2048];
  int tid = threadIdx.x, lane = tid & 63, w = tid >> 6;
  int widx = blockIdx.x * 4 + w;
  int b = widx / 320;
  int u = widx - b * 320;
  int qt, ci;
  if (u < 32)       { qt = u; ci = 0; }
  else if (u < 96)  { int v = u - 32; qt = 32 + (v >> 1); ci = v & 1; }
  else if (u < 192) { int v = u - 96; int q3 = v / 3; qt = 64 + q3; ci = v - 3 * q3; }
  else              { int v = u - 192; qt = 96 + (v >> 2); ci = v & 3; }
  int nkt = (qt >> 2) + 1;
  int t0 = ci * 8;
  int n = nkt - t0; if (n > 8) n = 8;
  int q0 = qt * 16;
  int c = lane & 15, g = lane >> 4;

  // Q fragments (A-operand: row = lane&15, k = 8*(lane>>4)+j); q pre-scaled
  const u16* qb = q_ws + ((size_t)b * T_ + q0 + c) * 64 + 8 * g;
  bf16x8 qa0 = *(const bf16x8*)qb;
  bf16x8 qa1 = *(const bf16x8*)(qb + 32);

  // per-lane bases: K rows (kv pos), Vt rows (head dim)
  const u16* kb0 = k_ws + ((size_t)b * T_ + t0 * 64 + c) * 64 + 8 * g;
  const u16* vb0 = vt_ws + (size_t)b * 64 * T_ + (size_t)c * T_ + t0 * 64 + 8 * g;

  bf16x8 kf[2][4][2], vf[4][2];
  auto LDK = [&](int t, int bu) {
#pragma unroll
    for (int nt = 0; nt < 4; ++nt) {
      const u16* p = kb0 + t * 4096 + nt * 1024;
      kf[bu][nt][0] = *(const bf16x8*)p;
      kf[bu][nt][1] = *(const bf16x8*)(p + 32);
    }
  };
  auto LDV = [&](int t) {
#pragma unroll
    for (int nt = 0; nt < 4; ++nt) {
      const u16* p = vb0 + (size_t)nt * 16 * T_ + t * 64;
      vf[nt][0] = *(const bf16x8*)p;
      vf[nt][1] = *(const bf16x8*)(p + 32);
    }
  };

  f32x4 accO[4];
#pragma unroll
  for (int i = 0; i < 4; ++i) accO[i] = (f32x4){0.f, 0.f, 0.f, 0.f};
  float m4[4] = {-__builtin_inff(), -__builtin_inff(), -__builtin_inff(), -__builtin_inff()};
  float l4[4] = {0.f, 0.f, 0.f, 0.f};
  char* pbase = sP + w * 2048;

  LDK(0, 0);
#pragma unroll
  for (int t = 0; t < 8; ++t) {
    if (t < n) {
      LDV(t);
      int bu = t & 1;
      // S = (Q/8) K^T
      f32x4 s4[4];
#pragma unroll
      for (int nt = 0; nt < 4; ++nt) {
        f32x4 z = (f32x4){0.f, 0.f, 0.f, 0.f};
        z = __builtin_amdgcn_mfma_f32_16x16x32_bf16(qa0, kf[bu][nt][0], z, 0, 0, 0);
        s4[nt] = __builtin_amdgcn_mfma_f32_16x16x32_bf16(qa1, kf[bu][nt][1], z, 0, 0, 0);
      }
      if (t + 1 < n) LDK(t + 1, bu ^ 1);
      // causal mask on the diagonal tile only
      int tt = t0 + t;
      if (tt == nkt - 1) {
        int colb = tt * 64 + c, rowb = q0 + (g << 2);
#pragma unroll
        for (int nt = 0; nt < 4; ++nt)
#pragma unroll
          for (int reg = 0; reg < 4; ++reg)
            if (colb + nt * 16 > rowb + reg) s4[nt][reg] = -__builtin_inff();
      }
      // online softmax: 16-lane groups hold one q-row's 64 cols
#pragma unroll
      for (int reg = 0; reg < 4; ++reg) {
        float smax = fmaxf(fmaxf(s4[0][reg], s4[1][reg]), fmaxf(s4[2][reg], s4[3][reg]));
#pragma unroll
        for (int d = 1; d < 16; d <<= 1) smax = fmaxf(smax, __shfl_xor(smax, d, 16));
        float mnew = fmaxf(m4[reg], smax);
        float sf = exp2f((m4[reg] - mnew) * LOG2E);
        float rsum = 0.f;
#pragma unroll
        for (int nt = 0; nt < 4; ++nt) {
          float p = exp2f((s4[nt][reg] - mnew) * LOG2E);
          s4[nt][reg] = p;
          rsum += p;
        }
#pragma unroll
        for (int d = 1; d < 16; d <<= 1) rsum += __shfl_xor(rsum, d, 16);
        l4[reg] = l4[reg] * sf + rsum;
        m4[reg] = mnew;
#pragma unroll
        for (int nt = 0; nt < 4; ++nt) accO[nt][reg] *= sf;
      }
      // P -> bf16 -> wave-private swizzled LDS (no barrier)
#pragma unroll
      for (int reg = 0; reg < 4; ++reg) {
        int ql = g * 4 + reg, swp = (ql & 7) << 4;
#pragma unroll
        for (int nt = 0; nt < 4; ++nt)
          *(u16*)(pbase + ql * 128 + ((2 * (nt * 16 + c)) ^ swp)) = bf2u((bf16)s4[nt][reg]);
      }
      // O += P V
#pragma unroll
      for (int ks = 0; ks < 2; ++ks) {
        bf16x8 pa = *(const bf16x8*)(pbase + c * 128 + ((ks * 64 + 16 * g) ^ ((c & 7) << 4)));
#pragma unroll
        for (int nt = 0; nt < 4; ++nt)
          accO[nt] = __builtin_amdgcn_mfma_f32_16x16x32_bf16(pa, vf[nt][ks], accO[nt], 0, 0, 0);
      }
    }
  }

  if (qt < 32) {
    // single chunk: normalize and write out directly
    float* ob = out + ((size_t)b * T_ + q0) * 64;
#pragma unroll
    for (int nt = 0; nt < 4; ++nt)
#pragma unroll
      for (int reg = 0; reg < 4; ++reg)
        ob[(size_t)(g * 4 + reg) * 64 + nt * 16 + c] = accO[nt][reg] / l4[reg];
  } else {
    float* pb = po + ((size_t)(b * 96 + (qt - 32)) * 4 + ci) * 1024;
#pragma unroll
    for (int nt = 0; nt < 4; ++nt)
#pragma unroll
      for (int reg = 0; reg < 4; ++reg)
        pb[(g * 4 + reg) * 64 + nt * 16 + c] = accO[nt][reg];
    if (c == 0) {
      float* mlp = ml + ((size_t)(b * 96 + (qt - 32)) * 4 + ci) * 32;
#pragma unroll
      for (int reg = 0; reg < 4; ++reg) {
        mlp[(g * 4 + reg) * 2]     = m4[reg];
        mlp[(g * 4 + reg) * 2 + 1] = l4[reg];
      }
    }
  }
}

// ---------------------------------------------------------------------------
// Kernel 4: merge split-KV partials for qt in [32,128). Block = one (b,qt).
// ---------------------------------------------------------------------------
__global__ __launch_bounds__(256) void merge_kernel(const float* __restrict__ po,
                                                    const float* __restrict__ ml,
                                                    float* __restrict__ out) {
  int bid = blockIdx.x;
  int b = bid / 96, qo = bid - b * 96;
  int qt = 32 + qo, nc = (qt >> 5) + 1;
  int tid = threadIdx.x, r = tid >> 4, h0 = (tid & 15) * 4;
  const float* mlb = ml + ((size_t)(b * 96 + qo) * 4) * 32 + r * 2;
  float m[4], l[4], wg[4];
  float M = -__builtin_inff();
#pragma unroll
  for (int ci = 0; ci < 4; ++ci) if (ci < nc) {
    m[ci] = mlb[ci * 32];
    l[ci] = mlb[ci * 32 + 1];
    M = fmaxf(M, m[ci]);
  }
  float L = 0.f;
#pragma unroll
  for (int ci = 0; ci < 4; ++ci) if (ci < nc) {
    wg[ci] = exp2f((m[ci] - M) * LOG2E);
    L += wg[ci] * l[ci];
  }
  const float* pb = po + ((size_t)(b * 96 + qo) * 4) * 1024 + r * 64 + h0;
  f32x4 acc = (f32x4){0.f, 0.f, 0.f, 0.f};
#pragma unroll
  for (int ci = 0; ci < 4; ++ci) if (ci < nc)
    acc += wg[ci] * *(const f32x4*)(pb + ci * 1024);
  float rL = 1.f / L;
  f32x4 res = acc * rL;
  *(f32x4*)(out + ((size_t)b * T_ + (size_t)qt * 16 + r) * 64 + h0) = res;
}

// ---------------------------------------------------------------------------
extern "C" void kernel_launch(void* const* d_in, const int* in_sizes, int n_in,
                              void* d_out, int out_size, void* d_ws, size_t ws_size,
                              hipStream_t stream) {
  const float* x  = (const float*)d_in[0];
  const float* Wk = (const float*)d_in[1];
  const float* Wq = (const float*)d_in[2];
  const float* Wv = (const float*)d_in[3];
  char* ws = (char*)d_ws;
  u16* q_ws   = (u16*)(ws);                //  0MB: [16384][64] bf16 (q * 0.125)
  u16* k_ws   = (u16*)(ws + 2 * MB);       //  2MB: [16384][64] bf16
  u16* vt_ws  = (u16*)(ws + 4 * MB);       //  4MB: [8][64][2048] bf16 (V^T)
  u16* wt_img = (u16*)(ws + 6 * MB);       //  6MB: 590KB swizzled weights
  float* po   = (float*)(ws + 7 * MB);     //  7MB: [8][96][4][16][64] f32
  float* ml   = (float*)(ws + 20 * MB);    // 20MB: [8][96][4][16][2] f32
  float* out = (float*)d_out;

  prepw_kernel<<<576, 256, 0, stream>>>(Wq, Wk, Wv, wt_img);
  proj_kernel<<<256, 512, 0, stream>>>(x, wt_img, q_ws, k_ws, vt_ws);
  attn_kernel<<<640, 256, 0, stream>>>(q_ws, k_ws, vt_ws, po, ml, out);
  merge_kernel<<<768, 256, 0, stream>>>(po, ml, out);
}

// Round 4
// 89.098 us; speedup vs baseline: 1.0306x; 1.0055x over previous
//
#include <hip/hip_runtime.h>
#include <hip/hip_bf16.h>

typedef unsigned short u16;
typedef unsigned int u32;
typedef __bf16 bf16;
typedef bf16 bf16x8 __attribute__((ext_vector_type(8)));
typedef float f32x4 __attribute__((ext_vector_type(4)));

#define B_ 8
#define T_ 2048
#define C_ 768
#define MB 1048576ull
#define SCALE_Q 0.1803368867f   /* 0.125 * log2(e): folds 1/sqrt(64) and exp->exp2 */
#define NEG_INF (-__builtin_inff())

#define AS1 __attribute__((address_space(1)))
#define AS3 __attribute__((address_space(3)))

__device__ __forceinline__ void g2l16(const void* g, void* l) {
  __builtin_amdgcn_global_load_lds((AS1 const void*)g, (AS3 void*)l, 16, 0, 0);
}
__device__ __forceinline__ u16 bf2u(bf16 h) {
  union { bf16 h; u16 u; } x; x.h = h; return x.u;
}
#define MFMA16(A, B, C) __builtin_amdgcn_mfma_f32_16x16x32_bf16((A), (B), (C), 0, 0, 0)

// ---------------------------------------------------------------------------
// Kernel 1: pre-swizzled Wt image: per K-step s (24), rows j=0..191
// (0..63 = Wq cols, 64..127 = Wk, 128..191 = Wv), 128B pitch,
// element (j, kk) at byte (s*192+j)*128 + ((2*kk) ^ ((j&7)<<4)).
// ---------------------------------------------------------------------------
__global__ __launch_bounds__(256) void prepw_kernel(const float* __restrict__ Wq,
                                                    const float* __restrict__ Wk,
                                                    const float* __restrict__ Wv,
                                                    u16* __restrict__ wt_img) {
  int tid = blockIdx.x * 256 + threadIdx.x;        // 3*768*64 = 147456 exactly
  int jj = tid & 63;
  int k  = (tid >> 6) % C_;
  int m  = tid / (64 * C_);
  const float* W = (m == 0) ? Wq : (m == 1 ? Wk : Wv);
  bf16 hv = (bf16)W[k * 64 + jj];
  int s = k >> 5, kk = k & 31, j = m * 64 + jj;
  int byteoff = (s * 192 + j) * 128 + ((2 * kk) ^ ((j & 7) << 4));
  *(u16*)((char*)wt_img + byteoff) = bf2u(hv);
}

// ---------------------------------------------------------------------------
// Kernel 2: projections. Block = 64 rows x 192 cols, 8 waves (4m x 2n).
// A-fragments direct global->reg (prefetched); weights double-buffered in LDS
// with counted vmcnt + raw barriers so the prefetch stays in flight.
// q scaled by 0.125*log2e; v written transposed.
// ---------------------------------------------------------------------------
__global__ __launch_bounds__(512) void proj_kernel(const float* __restrict__ x,
                                                   const u16* __restrict__ wt_img,
                                                   u16* __restrict__ q_ws,
                                                   u16* __restrict__ k_ws,
                                                   u16* __restrict__ vt_ws) {
  __shared__ __align__(16) char sB[2][192 * 128];
  int tid = threadIdx.x, lane = tid & 63, w = tid >> 6;
  int wm = w & 3, wn = w >> 2;
  int r0 = blockIdx.x * 64;
  int c = lane & 15, g = lane >> 4;

  f32x4 acc[6];
#pragma unroll
  for (int i = 0; i < 6; ++i) acc[i] = (f32x4){0.f, 0.f, 0.f, 0.f};

  const float* xrow = x + (size_t)(r0 + wm * 16 + c) * C_ + 8 * g;

  auto STAGE = [&](int s, int bs) {
    const char* wsrc = (const char*)wt_img + s * 24576;
#pragma unroll
    for (int i = 0; i < 3; ++i) {
      int off = (i * 512 + tid) * 16;
      g2l16(wsrc + off, sB[bs] + off);
    }
  };

  STAGE(0, 0);
  float4 a0 = *(const float4*)(xrow);
  float4 a1 = *(const float4*)(xrow + 4);

  for (int s = 0; s < 24; ++s) {
    int cur = s & 1;
    float4 b0, b1;
    if (s < 23) {
      STAGE(s + 1, cur ^ 1);
      b0 = *(const float4*)(xrow + (s + 1) * 32);
      b1 = *(const float4*)(xrow + (s + 1) * 32 + 4);
    }
    bf16x8 af;
    af[0] = (bf16)a0.x; af[1] = (bf16)a0.y; af[2] = (bf16)a0.z; af[3] = (bf16)a0.w;
    af[4] = (bf16)a1.x; af[5] = (bf16)a1.y; af[6] = (bf16)a1.z; af[7] = (bf16)a1.w;
    if (s < 23) {
      asm volatile("s_waitcnt vmcnt(5)" ::: "memory");  // drain stage(s); keep stage(s+1)+A(s+1)
    } else {
      asm volatile("s_waitcnt vmcnt(0)" ::: "memory");
    }
    __builtin_amdgcn_sched_barrier(0);
    __builtin_amdgcn_s_barrier();
    __builtin_amdgcn_sched_barrier(0);
    const char* bb = sB[cur];
#pragma unroll
    for (int nt = 0; nt < 6; ++nt) {
      int brow = wn * 96 + nt * 16 + c;
      bf16x8 bfr = *(const bf16x8*)(bb + brow * 128 + ((16 * g) ^ ((brow & 7) << 4)));
      acc[nt] = MFMA16(af, bfr, acc[nt]);
    }
    asm volatile("s_waitcnt lgkmcnt(0)" ::: "memory");
    __builtin_amdgcn_sched_barrier(0);
    __builtin_amdgcn_s_barrier();
    __builtin_amdgcn_sched_barrier(0);
    a0 = b0; a1 = b1;
  }

  // epilogue: D layout col = lane&15, row = (lane>>4)*4 + reg
#pragma unroll
  for (int nt = 0; nt < 6; ++nt) {
    int gc = wn * 96 + nt * 16;
    int m = gc >> 6;
    int h = (gc & 63) + c;
#pragma unroll
    for (int reg = 0; reg < 4; ++reg) {
      int r = r0 + wm * 16 + g * 4 + reg;
      float val = acc[nt][reg];
      if (m == 0)      q_ws[(size_t)r * 64 + h] = bf2u((bf16)(val * SCALE_Q));
      else if (m == 1) k_ws[(size_t)r * 64 + h] = bf2u((bf16)val);
      else             vt_ws[((size_t)(r >> 11) * 64 + h) * T_ + (r & 2047)] = bf2u((bf16)val);
    }
  }
}

// ---------------------------------------------------------------------------
// Kernel 3: causal flash attention, split-KV, swapped-operand MFMA.
// Wave = 16 q-rows x <=6 KV tiles of 64. S^T = mfma(K, Q): lane owns one
// q-row's k-slice -> lane-local softmax (2 shfl only). PV^T = mfma(Vt, P^T):
// rescale lane-uniform. K double-buffered in NAMED structs (static indexing).
// Waves/batch = 408 (chunk CH=6); b = blockIdx&7 pins batch to one XCD.
// ---------------------------------------------------------------------------
struct KF { bf16x8 f[4][2]; };

__device__ __forceinline__ void load_kf(KF& k, const u16* kbase, int t) {
#pragma unroll
  for (int nt = 0; nt < 4; ++nt) {
    const u16* p = kbase + t * 4096 + nt * 1024;
    k.f[nt][0] = *(const bf16x8*)p;
    k.f[nt][1] = *(const bf16x8*)(p + 32);
  }
}

__device__ __forceinline__ void tile_body(int t, const KF& kU, KF& kP, bool doPre,
                                          const u16* kbase, const u16* vbase,
                                          int t0, int nkt, int q0,
                                          const bf16x8& qb0, const bf16x8& qb1,
                                          int c, int g, char* pw,
                                          f32x4 (&accO)[4], float& mrun, float& lrun) {
  // V fragments for this tile (A-operand of PV^T): row h, k = kv pos
  KF v;
#pragma unroll
  for (int ht = 0; ht < 4; ++ht) {
    const u16* p = vbase + (size_t)ht * 16 * T_ + t * 64;
    v.f[ht][0] = *(const bf16x8*)p;
    v.f[ht][1] = *(const bf16x8*)(p + 32);
  }
  // S^T[kpos][q] = K . Q^T   (rows = kpos, cols = q = lane&15)
  f32x4 st[4];
#pragma unroll
  for (int nt = 0; nt < 4; ++nt) {
    f32x4 z = (f32x4){0.f, 0.f, 0.f, 0.f};
    z = MFMA16(kU.f[nt][0], qb0, z);
    st[nt] = MFMA16(kU.f[nt][1], qb1, z);
  }
  if (doPre) load_kf(kP, kbase, t + 1);
  int tt = t0 + t;
  if (tt == nkt - 1) {   // diagonal tile: mask kpos > q
    int qg = q0 + c, kb = tt * 64 + g * 4;
#pragma unroll
    for (int nt = 0; nt < 4; ++nt)
#pragma unroll
      for (int reg = 0; reg < 4; ++reg)
        if (kb + nt * 16 + reg > qg) st[nt][reg] = NEG_INF;
  }
  // lane-local softmax over the 16 held kpos + cross-group (xor16, xor32)
  float smax = st[0][0];
#pragma unroll
  for (int nt = 0; nt < 4; ++nt)
#pragma unroll
    for (int reg = 0; reg < 4; ++reg) smax = fmaxf(smax, st[nt][reg]);
  smax = fmaxf(smax, __shfl_xor(smax, 16));
  smax = fmaxf(smax, __shfl_xor(smax, 32));
  float mnew = fmaxf(mrun, smax);
  float sf = exp2f(mrun - mnew);
  float rsum = 0.f;
  u32 pk[4][2];
#pragma unroll
  for (int nt = 0; nt < 4; ++nt)
#pragma unroll
    for (int jp = 0; jp < 2; ++jp) {
      float p0 = exp2f(st[nt][2 * jp] - mnew);
      float p1 = exp2f(st[nt][2 * jp + 1] - mnew);
      rsum += p0 + p1;
      pk[nt][jp] = (u32)bf2u((bf16)p0) | ((u32)bf2u((bf16)p1) << 16);
    }
  rsum += __shfl_xor(rsum, 16);
  rsum += __shfl_xor(rsum, 32);
  lrun = lrun * sf + rsum;
  mrun = mnew;
#pragma unroll
  for (int ht = 0; ht < 4; ++ht) accO[ht] *= sf;
  // P (q-row c, 64 kpos) -> wave-private swizzled LDS row, packed b32 writes
  int swz = (c & 7) << 4;
#pragma unroll
  for (int nt = 0; nt < 4; ++nt)
#pragma unroll
    for (int jp = 0; jp < 2; ++jp) {
      int kpos = nt * 16 + g * 4 + 2 * jp;
      *(u32*)(pw + ((2 * kpos) ^ swz)) = pk[nt][jp];
    }
  // P^T as B-operand: col = q = c, k = kpos (8 consecutive)
  bf16x8 pf0 = *(const bf16x8*)(pw + ((16 * g) ^ swz));
  bf16x8 pf1 = *(const bf16x8*)(pw + ((64 + 16 * g) ^ swz));
#pragma unroll
  for (int ht = 0; ht < 4; ++ht) {
    accO[ht] = MFMA16(v.f[ht][0], pf0, accO[ht]);
    accO[ht] = MFMA16(v.f[ht][1], pf1, accO[ht]);
  }
}

__global__ __launch_bounds__(256) void attn_kernel(const u16* __restrict__ q_ws,
                                                   const u16* __restrict__ k_ws,
                                                   const u16* __restrict__ vt_ws,
                                                   float* __restrict__ po,
                                                   float* __restrict__ ml,
                                                   float* __restrict__ out) {
  __shared__ __align__(16) char sP[4 * 2048];
  int tid = threadIdx.x, lane = tid & 63, w = tid >> 6;
  int bid = blockIdx.x;
  int b = bid & 7;                       // batch -> XCD
  int u = (bid >> 3) * 4 + w;            // [0, 408)
  int m, lo;
  if (u < 24)       { m = 0; lo = 0; }
  else if (u < 72)  { m = 1; lo = 24; }
  else if (u < 144) { m = 2; lo = 72; }
  else if (u < 240) { m = 3; lo = 144; }
  else if (u < 360) { m = 4; lo = 240; }
  else              { m = 5; lo = 360; }
  int local = u - lo;
  int ci, qt;
  if (m < 5) { ci = local / 24; qt = 24 * m + (local - ci * 24); }
  else       { ci = local >> 3; qt = 120 + (local & 7); }
  int nkt = (qt >> 2) + 1;
  int t0 = ci * 6;
  int n = nkt - t0; if (n > 6) n = 6;
  int q0 = qt * 16;
  int c = lane & 15, g = lane >> 4;

  // Q as B-operand: col = q = c, k(h) = 8g+j; q pre-scaled by 0.125*log2e
  const u16* qb = q_ws + ((size_t)b * T_ + q0 + c) * 64 + 8 * g;
  bf16x8 qb0 = *(const bf16x8*)qb;
  bf16x8 qb1 = *(const bf16x8*)(qb + 32);

  const u16* kbase = k_ws + ((size_t)b * T_ + t0 * 64 + c) * 64 + 8 * g;
  const u16* vbase = vt_ws + (size_t)b * 64 * T_ + (size_t)c * T_ + t0 * 64 + 8 * g;

  f32x4 accO[4];
#pragma unroll
  for (int i = 0; i < 4; ++i) accO[i] = (f32x4){0.f, 0.f, 0.f, 0.f};
  float mrun = NEG_INF, lrun = 0.f;
  char* pw = sP + w * 2048 + c * 128;

  KF kA, kB;
  load_kf(kA, kbase, 0);
  /* explicit bodies, named dbuf structs — all register indexing static */
  tile_body(0, kA, kB, n > 1, kbase, vbase, t0, nkt, q0, qb0, qb1, c, g, pw, accO, mrun, lrun);
  if (n > 1) tile_body(1, kB, kA, n > 2, kbase, vbase, t0, nkt, q0, qb0, qb1, c, g, pw, accO, mrun, lrun);
  if (n > 2) tile_body(2, kA, kB, n > 3, kbase, vbase, t0, nkt, q0, qb0, qb1, c, g, pw, accO, mrun, lrun);
  if (n > 3) tile_body(3, kB, kA, n > 4, kbase, vbase, t0, nkt, q0, qb0, qb1, c, g, pw, accO, mrun, lrun);
  if (n > 4) tile_body(4, kA, kB, n > 5, kbase, vbase, t0, nkt, q0, qb0, qb1, c, g, pw, accO, mrun, lrun);
  if (n > 5) tile_body(5, kB, kA, false,  kbase, vbase, t0, nkt, q0, qb0, qb1, c, g, pw, accO, mrun, lrun);

  if (u < 24) {
    // single chunk: normalize, write out (accO is out^T: lane holds col q=c)
    float rl = 1.f / lrun;
    float* ob = out + ((size_t)b * T_ + q0 + c) * 64;
#pragma unroll
    for (int ht = 0; ht < 4; ++ht)
#pragma unroll
      for (int reg = 0; reg < 4; ++reg)
        ob[ht * 16 + g * 4 + reg] = accO[ht][reg] * rl;
  } else {
    int slot = b * 384 + (u - 24);
    float* pb = po + (size_t)slot * 1024;   // [64 h][16 q] f32
#pragma unroll
    for (int ht = 0; ht < 4; ++ht)
#pragma unroll
      for (int reg = 0; reg < 4; ++reg)
        pb[(ht * 16 + g * 4 + reg) * 16 + c] = accO[ht][reg];
    if (g == 0) {
      float2 v2; v2.x = mrun; v2.y = lrun;
      *(float2*)(ml + (size_t)slot * 32 + c * 2) = v2;
    }
  }
}

// ---------------------------------------------------------------------------
// Kernel 4: merge split-KV partials for qt in [24,128). Block = one (b,qt).
// Grid MUST be 104*8 = 832 (qt 24..127 only).
// ---------------------------------------------------------------------------
__global__ __launch_bounds__(256) void merge_kernel(const float* __restrict__ po,
                                                    const float* __restrict__ ml,
                                                    float* __restrict__ out) {
  int bid = blockIdx.x;                 // 832 = 104 * 8
  int b = bid & 7, qi = bid >> 3;
  int qt = 24 + qi;                     // [24, 128)
  int m = qt / 24;                      // 1..5
  int width = (m < 5) ? 24 : 8;
  int lo = 12 * m * (m + 1);
  int nc = m + 1;
  int rbase = qt - 24 * m;
  int q = threadIdx.x & 15, hq = threadIdx.x >> 4;   // hq in [0,16): h0 = hq*4
  int sbase = b * 384 + lo + rbase - 24;

  float M = NEG_INF;
  for (int ci = 0; ci < nc; ++ci) {
    float mv = ml[(size_t)(sbase + ci * width) * 32 + q * 2];
    M = fmaxf(M, mv);
  }
  float L = 0.f;
  f32x4 acc = (f32x4){0.f, 0.f, 0.f, 0.f};
  for (int ci = 0; ci < nc; ++ci) {
    int sl = sbase + ci * width;
    float2 mlv = *(const float2*)(ml + (size_t)sl * 32 + q * 2);
    float wgt = exp2f(mlv.x - M);
    L += wgt * mlv.y;
    const float* pb = po + (size_t)sl * 1024 + hq * 64 + q;
    acc[0] += wgt * pb[0];
    acc[1] += wgt * pb[16];
    acc[2] += wgt * pb[32];
    acc[3] += wgt * pb[48];
  }
  float rl = 1.f / L;
  f32x4 res = acc * rl;
  *(f32x4*)(out + ((size_t)b * T_ + (size_t)qt * 16 + q) * 64 + hq * 4) = res;
}

// ---------------------------------------------------------------------------
extern "C" void kernel_launch(void* const* d_in, const int* in_sizes, int n_in,
                              void* d_out, int out_size, void* d_ws, size_t ws_size,
                              hipStream_t stream) {
  const float* x  = (const float*)d_in[0];
  const float* Wk = (const float*)d_in[1];
  const float* Wq = (const float*)d_in[2];
  const float* Wv = (const float*)d_in[3];
  char* ws = (char*)d_ws;
  u16* q_ws   = (u16*)(ws);                //  0MB: [16384][64] bf16 (q * 0.125*log2e)
  u16* k_ws   = (u16*)(ws + 2 * MB);       //  2MB: [16384][64] bf16
  u16* vt_ws  = (u16*)(ws + 4 * MB);       //  4MB: [8][64][2048] bf16 (V^T)
  u16* wt_img = (u16*)(ws + 6 * MB);       //  6MB: 590KB swizzled weights
  float* po   = (float*)(ws + 7 * MB);     //  7MB: 3072 slots x [64][16] f32 = 12.6MB
  float* ml   = (float*)(ws + 20 * MB);    // 20MB: 3072 x [16][2] f32 = 393KB
  float* out = (float*)d_out;

  prepw_kernel<<<576, 256, 0, stream>>>(Wq, Wk, Wv, wt_img);
  proj_kernel<<<256, 512, 0, stream>>>(x, wt_img, q_ws, k_ws, vt_ws);
  attn_kernel<<<816, 256, 0, stream>>>(q_ws, k_ws, vt_ws, po, ml, out);
  merge_kernel<<<832, 256, 0, stream>>>(po, ml, out);
}

// Round 5
// 58.959 us; speedup vs baseline: 1.5575x; 1.5112x over previous
//
#include <hip/hip_runtime.h>
#include <hip/hip_bf16.h>

typedef unsigned short u16;
typedef unsigned int u32;
typedef __bf16 bf16;
typedef bf16 bf16x8 __attribute__((ext_vector_type(8)));
typedef float f32x4 __attribute__((ext_vector_type(4)));

#define B_ 8
#define T_ 2048
#define C_ 768
#define MB 1048576ull
#define SCALE_Q 0.1803368867f   /* 0.125 * log2(e): folds 1/sqrt(64) and exp->exp2 */
#define NEG_INF (-__builtin_inff())

#define AS1 __attribute__((address_space(1)))
#define AS3 __attribute__((address_space(3)))

__device__ __forceinline__ void g2l16(const void* g, void* l) {
  __builtin_amdgcn_global_load_lds((AS1 const void*)g, (AS3 void*)l, 16, 0, 0);
}
__device__ __forceinline__ u16 bf2u(bf16 h) {
  union { bf16 h; u16 u; } x; x.h = h; return x.u;
}
#define MFMA16(A, B, C) __builtin_amdgcn_mfma_f32_16x16x32_bf16((A), (B), (C), 0, 0, 0)
#define SBAR() __builtin_amdgcn_sched_barrier(0)

// ---------------------------------------------------------------------------
// Kernel 1: pre-swizzled Wt image: per K-step s (24), rows j=0..191
// (0..63 = Wq cols, 64..127 = Wk, 128..191 = Wv), 128B pitch,
// element (j, kk) at byte (s*192+j)*128 + ((2*kk) ^ ((j&7)<<4)).
// ---------------------------------------------------------------------------
__global__ __launch_bounds__(256) void prepw_kernel(const float* __restrict__ Wq,
                                                    const float* __restrict__ Wk,
                                                    const float* __restrict__ Wv,
                                                    u16* __restrict__ wt_img) {
  int tid = blockIdx.x * 256 + threadIdx.x;        // 3*768*64 = 147456 exactly
  int jj = tid & 63;
  int k  = (tid >> 6) % C_;
  int m  = tid / (64 * C_);
  const float* W = (m == 0) ? Wq : (m == 1 ? Wk : Wv);
  bf16 hv = (bf16)W[k * 64 + jj];
  int s = k >> 5, kk = k & 31, j = m * 64 + jj;
  int byteoff = (s * 192 + j) * 128 + ((2 * kk) ^ ((j & 7) << 4));
  *(u16*)((char*)wt_img + byteoff) = bf2u(hv);
}

// ---------------------------------------------------------------------------
// Kernel 2: projections. Block = 64 rows x 192 cols, 8 waves (4m x 2n).
// x AND weights staged via g2l16 (fully coalesced), both double-buffered,
// counted vmcnt. x-tile XOR-swizzled via pre-swizzled per-lane source.
// Outputs: q row-major (scaled by 0.125*log2e); k/v as fragment-ordered tile
// images: [b][t][nt|ht][jp][g][c][j] u16 so attn loads are lane-contiguous.
// ---------------------------------------------------------------------------
__global__ __launch_bounds__(512) void proj_kernel(const float* __restrict__ x,
                                                   const u16* __restrict__ wt_img,
                                                   u16* __restrict__ q_ws,
                                                   u16* __restrict__ k_img,
                                                   u16* __restrict__ vt_img) {
  __shared__ __align__(16) char xt[2][8192];
  __shared__ __align__(16) char wt[2][24576];
  int tid = threadIdx.x, lane = tid & 63, w = tid >> 6;
  int wm = w & 3, wn = w >> 2;
  int r0 = blockIdx.x * 64;
  int c = lane & 15, g = lane >> 4;

  f32x4 acc[6];
#pragma unroll
  for (int i = 0; i < 6; ++i) acc[i] = (f32x4){0.f, 0.f, 0.f, 0.f};

  // x staging: thread t covers image slot (row=t>>3, ch=t&7); source chunk
  // pre-swizzled so LDS content at [row][ch] = x chunk (ch ^ (row&7)).
  int srow = tid >> 3, sch = tid & 7;
  const float* srcx = x + (size_t)(r0 + srow) * C_ + ((sch ^ (srow & 7)) * 4);

  auto STAGE = [&](int s, int bs) {
    g2l16(srcx + s * 32, xt[bs] + tid * 16);
    const char* wsrc = (const char*)wt_img + s * 24576;
#pragma unroll
    for (int i = 0; i < 3; ++i) {
      int off = (i * 512 + tid) * 16;
      g2l16(wsrc + off, wt[bs] + off);
    }
  };

  STAGE(0, 0);

  int arow = wm * 16 + c;
  int aswz = (arow & 7) << 4;
  const char* xrowp = nullptr;  // computed per-iter from xt[cur]

  for (int s = 0; s < 24; ++s) {
    int cur = s & 1;
    if (s < 23) {
      STAGE(s + 1, cur ^ 1);
      asm volatile("s_waitcnt vmcnt(4)" ::: "memory");  // stage(s) landed
    } else {
      asm volatile("s_waitcnt vmcnt(0)" ::: "memory");
    }
    SBAR();
    __builtin_amdgcn_s_barrier();
    SBAR();
    // A fragment: rows of x-tile, f32 cols 8g..8g+7 -> bf16x8
    xrowp = xt[cur] + arow * 128;
    f32x4 f0 = *(const f32x4*)(xrowp + (((2 * g) * 16) ^ aswz));
    f32x4 f1 = *(const f32x4*)(xrowp + (((2 * g + 1) * 16) ^ aswz));
    bf16x8 af;
    af[0] = (bf16)f0[0]; af[1] = (bf16)f0[1]; af[2] = (bf16)f0[2]; af[3] = (bf16)f0[3];
    af[4] = (bf16)f1[0]; af[5] = (bf16)f1[1]; af[6] = (bf16)f1[2]; af[7] = (bf16)f1[3];
    const char* bb = wt[cur];
#pragma unroll
    for (int nt = 0; nt < 6; ++nt) {
      int brow = wn * 96 + nt * 16 + c;
      bf16x8 bfr = *(const bf16x8*)(bb + brow * 128 + ((16 * g) ^ ((brow & 7) << 4)));
      acc[nt] = MFMA16(af, bfr, acc[nt]);
    }
    asm volatile("s_waitcnt lgkmcnt(0)" ::: "memory");
    SBAR();
    __builtin_amdgcn_s_barrier();
    SBAR();
  }

  // epilogue: D layout col = lane&15, row = (lane>>4)*4 + reg
#pragma unroll
  for (int nt = 0; nt < 6; ++nt) {
    int gc = wn * 96 + nt * 16;
    int m = gc >> 6;
    int h = (gc & 63) + c;
#pragma unroll
    for (int reg = 0; reg < 4; ++reg) {
      int r = r0 + wm * 16 + g * 4 + reg;   // token index
      float val = acc[nt][reg];
      int bb2 = r >> 11, rr = r & 2047, t = rr >> 6;
      if (m == 0) {
        q_ws[(size_t)r * 64 + h] = bf2u((bf16)(val * SCALE_Q));
      } else if (m == 1) {
        // K tile image: kpos_local = 16*nt + c -> (ntk, ck); h -> (jp, gg, jj)
        int ntk = (rr >> 4) & 3, ck = rr & 15;
        int jp = h >> 5, gg = (h >> 3) & 3, jj = h & 7;
        k_img[((size_t)(bb2 * 32 + t)) * 4096 + ntk * 1024 + jp * 512 + gg * 128 + ck * 8 + jj] = bf2u((bf16)val);
      } else {
        // V tile image: h -> (ht, cv); kpos_local = rr&63 -> (jpv, gv, jv)
        int ht = h >> 4, cv = h & 15;
        int jpv = (rr >> 5) & 1, gv = (rr >> 3) & 3, jv = rr & 7;
        vt_img[((size_t)(bb2 * 32 + t)) * 4096 + ht * 1024 + jpv * 512 + gv * 128 + cv * 8 + jv] = bf2u((bf16)val);
      }
    }
  }
}

// ---------------------------------------------------------------------------
// Kernel 3: causal flash attention, split-KV, swapped-operand MFMA.
// Wave = 16 q-rows x <=6 KV tiles of 64. Fragment-ordered K/V images make
// every load instruction a contiguous 1KB wave transaction (base + lane*8).
// S^T = mfma(K, Q): lane-local softmax (2 shfl). PV^T = mfma(Vt, P^T).
// K double-buffered in NAMED structs (static indexing). 408 waves/batch.
// ---------------------------------------------------------------------------
struct KF { bf16x8 f[4][2]; };

__device__ __forceinline__ void load_kf(KF& k, const u16* kbase, int t) {
#pragma unroll
  for (int nt = 0; nt < 4; ++nt)
#pragma unroll
    for (int jp = 0; jp < 2; ++jp)
      k.f[nt][jp] = *(const bf16x8*)(kbase + (size_t)t * 4096 + nt * 1024 + jp * 512);
}

__device__ __forceinline__ void tile_body(int t, const KF& kU, KF& kP, bool doPre,
                                          const u16* kbase, const u16* vbase,
                                          int t0, int nkt, int q0,
                                          const bf16x8& qb0, const bf16x8& qb1,
                                          int c, int g, char* pw,
                                          f32x4 (&accO)[4], float& mrun, float& lrun) {
  // V fragments for this tile (A-operand of PV^T), contiguous loads
  KF v;
#pragma unroll
  for (int ht = 0; ht < 4; ++ht)
#pragma unroll
    for (int jp = 0; jp < 2; ++jp)
      v.f[ht][jp] = *(const bf16x8*)(vbase + (size_t)t * 4096 + ht * 1024 + jp * 512);
  SBAR();
  // S^T[kpos][q] = K . Q^T   (rows = kpos, cols = q = lane&15)
  f32x4 st[4];
#pragma unroll
  for (int nt = 0; nt < 4; ++nt) {
    f32x4 z = (f32x4){0.f, 0.f, 0.f, 0.f};
    z = MFMA16(kU.f[nt][0], qb0, z);
    st[nt] = MFMA16(kU.f[nt][1], qb1, z);
  }
  if (doPre) load_kf(kP, kbase, t + 1);
  SBAR();
  int tt = t0 + t;
  if (tt == nkt - 1) {   // diagonal tile: mask kpos > q
    int qg = q0 + c, kb = tt * 64 + g * 4;
#pragma unroll
    for (int nt = 0; nt < 4; ++nt)
#pragma unroll
      for (int reg = 0; reg < 4; ++reg)
        if (kb + nt * 16 + reg > qg) st[nt][reg] = NEG_INF;
  }
  // lane-local softmax over 16 held kpos + cross-group (xor16, xor32)
  float smax = st[0][0];
#pragma unroll
  for (int nt = 0; nt < 4; ++nt)
#pragma unroll
    for (int reg = 0; reg < 4; ++reg) smax = fmaxf(smax, st[nt][reg]);
  smax = fmaxf(smax, __shfl_xor(smax, 16));
  smax = fmaxf(smax, __shfl_xor(smax, 32));
  float mnew = fmaxf(mrun, smax);
  float sf = exp2f(mrun - mnew);
  float rsum = 0.f;
  u32 pk[4][2];
#pragma unroll
  for (int nt = 0; nt < 4; ++nt)
#pragma unroll
    for (int jp = 0; jp < 2; ++jp) {
      float p0 = exp2f(st[nt][2 * jp] - mnew);
      float p1 = exp2f(st[nt][2 * jp + 1] - mnew);
      rsum += p0 + p1;
      pk[nt][jp] = (u32)bf2u((bf16)p0) | ((u32)bf2u((bf16)p1) << 16);
    }
  rsum += __shfl_xor(rsum, 16);
  rsum += __shfl_xor(rsum, 32);
  lrun = lrun * sf + rsum;
  mrun = mnew;
#pragma unroll
  for (int ht = 0; ht < 4; ++ht) accO[ht] *= sf;
  // P (q-row c, 64 kpos) -> wave-private swizzled LDS row, packed b32 writes
  int swz = (c & 7) << 4;
#pragma unroll
  for (int nt = 0; nt < 4; ++nt)
#pragma unroll
    for (int jp = 0; jp < 2; ++jp) {
      int kpos = nt * 16 + g * 4 + 2 * jp;
      *(u32*)(pw + ((2 * kpos) ^ swz)) = pk[nt][jp];
    }
  // P^T as B-operand: col = q = c, k = kpos (8 consecutive)
  bf16x8 pf0 = *(const bf16x8*)(pw + ((16 * g) ^ swz));
  bf16x8 pf1 = *(const bf16x8*)(pw + ((64 + 16 * g) ^ swz));
#pragma unroll
  for (int ht = 0; ht < 4; ++ht) {
    accO[ht] = MFMA16(v.f[ht][0], pf0, accO[ht]);
    accO[ht] = MFMA16(v.f[ht][1], pf1, accO[ht]);
  }
}

__global__ __launch_bounds__(256) void attn_kernel(const u16* __restrict__ q_ws,
                                                   const u16* __restrict__ k_img,
                                                   const u16* __restrict__ vt_img,
                                                   float* __restrict__ po,
                                                   float* __restrict__ ml,
                                                   float* __restrict__ out) {
  __shared__ __align__(16) char sP[4 * 2048];
  int tid = threadIdx.x, lane = tid & 63, w = tid >> 6;
  int bid = blockIdx.x;
  int b = bid & 7;                       // batch -> XCD
  int u = (bid >> 3) * 4 + w;            // [0, 408)
  int m, lo;
  if (u < 24)       { m = 0; lo = 0; }
  else if (u < 72)  { m = 1; lo = 24; }
  else if (u < 144) { m = 2; lo = 72; }
  else if (u < 240) { m = 3; lo = 144; }
  else if (u < 360) { m = 4; lo = 240; }
  else              { m = 5; lo = 360; }
  int local = u - lo;
  int ci, qt;
  if (m < 5) { ci = local / 24; qt = 24 * m + (local - ci * 24); }
  else       { ci = local >> 3; qt = 120 + (local & 7); }
  int nkt = (qt >> 2) + 1;
  int t0 = ci * 6;
  int n = nkt - t0; if (n > 6) n = 6;
  int q0 = qt * 16;
  int c = lane & 15, g = lane >> 4;

  // Q as B-operand: col = q = c, k(h) = 8g+j; q pre-scaled by 0.125*log2e
  const u16* qb = q_ws + ((size_t)b * T_ + q0 + c) * 64 + 8 * g;
  bf16x8 qb0 = *(const bf16x8*)qb;
  bf16x8 qb1 = *(const bf16x8*)(qb + 32);

  const u16* kbase = k_img + ((size_t)(b * 32 + t0)) * 4096 + lane * 8;
  const u16* vbase = vt_img + ((size_t)(b * 32 + t0)) * 4096 + lane * 8;

  f32x4 accO[4];
#pragma unroll
  for (int i = 0; i < 4; ++i) accO[i] = (f32x4){0.f, 0.f, 0.f, 0.f};
  float mrun = NEG_INF, lrun = 0.f;
  char* pw = sP + w * 2048 + c * 128;

  KF kA, kB;
  load_kf(kA, kbase, 0);
  /* explicit bodies, named dbuf structs — all register indexing static */
  tile_body(0, kA, kB, n > 1, kbase, vbase, t0, nkt, q0, qb0, qb1, c, g, pw, accO, mrun, lrun);
  if (n > 1) tile_body(1, kB, kA, n > 2, kbase, vbase, t0, nkt, q0, qb0, qb1, c, g, pw, accO, mrun, lrun);
  if (n > 2) tile_body(2, kA, kB, n > 3, kbase, vbase, t0, nkt, q0, qb0, qb1, c, g, pw, accO, mrun, lrun);
  if (n > 3) tile_body(3, kB, kA, n > 4, kbase, vbase, t0, nkt, q0, qb0, qb1, c, g, pw, accO, mrun, lrun);
  if (n > 4) tile_body(4, kA, kB, n > 5, kbase, vbase, t0, nkt, q0, qb0, qb1, c, g, pw, accO, mrun, lrun);
  if (n > 5) tile_body(5, kB, kA, false,  kbase, vbase, t0, nkt, q0, qb0, qb1, c, g, pw, accO, mrun, lrun);

  if (u < 24) {
    // single chunk: normalize, write out (accO is out^T: lane holds col q=c)
    float rl = 1.f / lrun;
    float* ob = out + ((size_t)b * T_ + q0 + c) * 64;
#pragma unroll
    for (int ht = 0; ht < 4; ++ht)
#pragma unroll
      for (int reg = 0; reg < 4; ++reg)
        ob[ht * 16 + g * 4 + reg] = accO[ht][reg] * rl;
  } else {
    int slot = b * 384 + (u - 24);
    float* pb = po + (size_t)slot * 1024;   // [64 h][16 q] f32
#pragma unroll
    for (int ht = 0; ht < 4; ++ht)
#pragma unroll
      for (int reg = 0; reg < 4; ++reg)
        pb[(ht * 16 + g * 4 + reg) * 16 + c] = accO[ht][reg];
    if (g == 0) {
      float2 v2; v2.x = mrun; v2.y = lrun;
      *(float2*)(ml + (size_t)slot * 32 + c * 2) = v2;
    }
  }
}

// ---------------------------------------------------------------------------
// Kernel 4: merge split-KV partials for qt in [24,128). Block = one (b,qt).
// Grid MUST be 104*8 = 832 (qt 24..127 only).
// ---------------------------------------------------------------------------
__global__ __launch_bounds__(256) void merge_kernel(const float* __restrict__ po,
                                                    const float* __restrict__ ml,
                                                    float* __restrict__ out) {
  int bid = blockIdx.x;                 // 832 = 104 * 8
  int b = bid & 7, qi = bid >> 3;
  int qt = 24 + qi;                     // [24, 128)
  int m = qt / 24;                      // 1..5
  int width = (m < 5) ? 24 : 8;
  int lo = 12 * m * (m + 1);
  int nc = m + 1;
  int rbase = qt - 24 * m;
  int q = threadIdx.x & 15, hq = threadIdx.x >> 4;   // hq in [0,16): h0 = hq*4
  int sbase = b * 384 + lo + rbase - 24;

  float M = NEG_INF;
  for (int ci = 0; ci < nc; ++ci) {
    float mv = ml[(size_t)(sbase + ci * width) * 32 + q * 2];
    M = fmaxf(M, mv);
  }
  float L = 0.f;
  f32x4 acc = (f32x4){0.f, 0.f, 0.f, 0.f};
  for (int ci = 0; ci < nc; ++ci) {
    int sl = sbase + ci * width;
    float2 mlv = *(const float2*)(ml + (size_t)sl * 32 + q * 2);
    float wgt = exp2f(mlv.x - M);
    L += wgt * mlv.y;
    const float* pb = po + (size_t)sl * 1024 + hq * 64 + q;
    acc[0] += wgt * pb[0];
    acc[1] += wgt * pb[16];
    acc[2] += wgt * pb[32];
    acc[3] += wgt * pb[48];
  }
  float rl = 1.f / L;
  f32x4 res = acc * rl;
  *(f32x4*)(out + ((size_t)b * T_ + (size_t)qt * 16 + q) * 64 + hq * 4) = res;
}

// ---------------------------------------------------------------------------
extern "C" void kernel_launch(void* const* d_in, const int* in_sizes, int n_in,
                              void* d_out, int out_size, void* d_ws, size_t ws_size,
                              hipStream_t stream) {
  const float* x  = (const float*)d_in[0];
  const float* Wk = (const float*)d_in[1];
  const float* Wq = (const float*)d_in[2];
  const float* Wv = (const float*)d_in[3];
  char* ws = (char*)d_ws;
  u16* q_ws   = (u16*)(ws);                //  0MB: [16384][64] bf16 (q * 0.125*log2e)
  u16* k_img  = (u16*)(ws + 2 * MB);       //  2MB: [8][32][4096] u16 tile image
  u16* vt_img = (u16*)(ws + 4 * MB);       //  4MB: [8][32][4096] u16 tile image
  u16* wt_img = (u16*)(ws + 6 * MB);       //  6MB: 590KB swizzled weights
  float* po   = (float*)(ws + 7 * MB);     //  7MB: 3072 slots x [64][16] f32 = 12.6MB
  float* ml   = (float*)(ws + 20 * MB);    // 20MB: 3072 x [16][2] f32 = 393KB
  float* out = (float*)d_out;

  prepw_kernel<<<576, 256, 0, stream>>>(Wq, Wk, Wv, wt_img);
  proj_kernel<<<256, 512, 0, stream>>>(x, wt_img, q_ws, k_img, vt_img);
  attn_kernel<<<816, 256, 0, stream>>>(q_ws, k_img, vt_img, po, ml, out);
  merge_kernel<<<832, 256, 0, stream>>>(po, ml, out);
}

// Round 6
// 52.471 us; speedup vs baseline: 1.7501x; 1.1237x over previous
//
#include <hip/hip_runtime.h>
#include <hip/hip_bf16.h>

typedef unsigned short u16;
typedef unsigned int u32;
typedef __bf16 bf16;
typedef bf16 bf16x8 __attribute__((ext_vector_type(8)));
typedef float f32x4 __attribute__((ext_vector_type(4)));

#define B_ 8
#define T_ 2048
#define C_ 768
#define MB 1048576ull
#define SCALE_Q 0.1803368867f   /* 0.125 * log2(e): folds 1/sqrt(64) and exp->exp2 */
#define NEG_INF (-__builtin_inff())

#define AS1 __attribute__((address_space(1)))
#define AS3 __attribute__((address_space(3)))

__device__ __forceinline__ void g2l16(const void* g, void* l) {
  __builtin_amdgcn_global_load_lds((AS1 const void*)g, (AS3 void*)l, 16, 0, 0);
}
__device__ __forceinline__ u16 bf2u(bf16 h) {
  union { bf16 h; u16 u; } x; x.h = h; return x.u;
}
#define MFMA16(A, B, C) __builtin_amdgcn_mfma_f32_16x16x32_bf16((A), (B), (C), 0, 0, 0)
#define SBAR() __builtin_amdgcn_sched_barrier(0)

// ---------------------------------------------------------------------------
// Kernel 1: pre-swizzled Wt image: per K-step s (24), rows j=0..191
// (0..63 = Wq cols, 64..127 = Wk, 128..191 = Wv), 128B pitch,
// element (j, kk) at byte (s*192+j)*128 + ((2*kk) ^ ((j&7)<<4)).
// ---------------------------------------------------------------------------
__global__ __launch_bounds__(256) void prepw_kernel(const float* __restrict__ Wq,
                                                    const float* __restrict__ Wk,
                                                    const float* __restrict__ Wv,
                                                    u16* __restrict__ wt_img) {
  int tid = blockIdx.x * 256 + threadIdx.x;        // 3*768*64 = 147456 exactly
  int jj = tid & 63;
  int k  = (tid >> 6) % C_;
  int m  = tid / (64 * C_);
  const float* W = (m == 0) ? Wq : (m == 1 ? Wk : Wv);
  bf16 hv = (bf16)W[k * 64 + jj];
  int s = k >> 5, kk = k & 31, j = m * 64 + jj;
  int byteoff = (s * 192 + j) * 128 + ((2 * kk) ^ ((j & 7) << 4));
  *(u16*)((char*)wt_img + byteoff) = bf2u(hv);
}

// ---------------------------------------------------------------------------
// Kernel 2: projections. Block = 1024 thr (16 waves, 4m x 4n), 64 rows x 192
// cols, K-loop 24x32. 4 LDS buffers, 2-deep prefetch, counted vmcnt(4),
// ONE barrier per step (4-buf rotation keeps reader s%4 vs stager (s+3)%4
// disjoint under barrier-bounded skew<=1). All staging via g2l16 (2/thread).
// ---------------------------------------------------------------------------
__global__ __launch_bounds__(1024) void proj_kernel(const float* __restrict__ x,
                                                    const u16* __restrict__ wt_img,
                                                    u16* __restrict__ q_ws,
                                                    u16* __restrict__ k_img,
                                                    u16* __restrict__ vt_img) {
  __shared__ __align__(16) char xt[4][8192];
  __shared__ __align__(16) char wt[4][24576];
  int tid = threadIdx.x, lane = tid & 63, w = tid >> 6;
  int wm = w & 3, wn = w >> 2;           // wm: m-tile (16 rows); wn: 48-col band
  int r0 = blockIdx.x * 64;
  int c = lane & 15, g = lane >> 4;

  f32x4 acc[3];
#pragma unroll
  for (int i = 0; i < 3; ++i) acc[i] = (f32x4){0.f, 0.f, 0.f, 0.f};

  // staging map: all threads stage wt slot tid; tid<512 also wt slot 1024+tid;
  // tid>=512 stages x slot xs=tid-512 (row=xs>>3, ch=xs&7, pre-swizzled src).
  int xs = tid - 512;
  int xrow_s = (xs >> 3) & 63, xch = xs & 7;
  const float* srcx = x + (size_t)(r0 + xrow_s) * C_ + ((xch ^ (xrow_s & 7)) * 4);

  auto STAGE = [&](int s, int bs) {
    const char* wsrc = (const char*)wt_img + s * 24576;
    g2l16(wsrc + tid * 16, wt[bs] + tid * 16);
    if (tid < 512) {
      g2l16(wsrc + (1024 + tid) * 16, wt[bs] + (1024 + tid) * 16);
    } else {
      g2l16(srcx + s * 32, xt[bs] + xs * 16);
    }
  };

  STAGE(0, 0);
  STAGE(1, 1);

  int arow = wm * 16 + c;
  int aswz = (arow & 7) << 4;

  for (int s = 0; s < 24; ++s) {
    int cur = s & 3;
    if (s < 22) {
      STAGE(s + 2, (s + 2) & 3);
      asm volatile("s_waitcnt vmcnt(4)" ::: "memory");   // stage(s) landed
    } else if (s == 22) {
      asm volatile("s_waitcnt vmcnt(2)" ::: "memory");
    } else {
      asm volatile("s_waitcnt vmcnt(0)" ::: "memory");
    }
    SBAR();
    __builtin_amdgcn_s_barrier();
    SBAR();
    // A fragment: x-tile row arow, f32 chunks 2g, 2g+1 (swizzled) -> bf16x8
    const char* xrowp = xt[cur] + arow * 128;
    f32x4 f0 = *(const f32x4*)(xrowp + (((2 * g) * 16) ^ aswz));
    f32x4 f1 = *(const f32x4*)(xrowp + (((2 * g + 1) * 16) ^ aswz));
    bf16x8 af;
    af[0] = (bf16)f0[0]; af[1] = (bf16)f0[1]; af[2] = (bf16)f0[2]; af[3] = (bf16)f0[3];
    af[4] = (bf16)f1[0]; af[5] = (bf16)f1[1]; af[6] = (bf16)f1[2]; af[7] = (bf16)f1[3];
    const char* bb = wt[cur];
#pragma unroll
    for (int nt = 0; nt < 3; ++nt) {
      int brow = wn * 48 + nt * 16 + c;
      bf16x8 bfr = *(const bf16x8*)(bb + brow * 128 + ((16 * g) ^ ((brow & 7) << 4)));
      acc[nt] = MFMA16(af, bfr, acc[nt]);
    }
  }

  // epilogue: D layout col = lane&15, row = (lane>>4)*4 + reg
#pragma unroll
  for (int nt = 0; nt < 3; ++nt) {
    int gc = wn * 48 + nt * 16;
    int m = gc >> 6;
    int h = (gc & 63) + c;
#pragma unroll
    for (int reg = 0; reg < 4; ++reg) {
      int r = r0 + wm * 16 + g * 4 + reg;   // token index
      float val = acc[nt][reg];
      int bb2 = r >> 11, rr = r & 2047, t = rr >> 6;
      if (m == 0) {
        q_ws[(size_t)r * 64 + h] = bf2u((bf16)(val * SCALE_Q));
      } else if (m == 1) {
        // K tile image: kpos_local = rr&63 -> (ntk, ck); h -> (jp, gg, jj)
        int ntk = (rr >> 4) & 3, ck = rr & 15;
        int jp = h >> 5, gg = (h >> 3) & 3, jj = h & 7;
        k_img[((size_t)(bb2 * 32 + t)) * 4096 + ntk * 1024 + jp * 512 + gg * 128 + ck * 8 + jj] = bf2u((bf16)val);
      } else {
        // V tile image: h -> (ht, cv); kpos_local = rr&63 -> (jpv, gv, jv)
        int ht = h >> 4, cv = h & 15;
        int jpv = (rr >> 5) & 1, gv = (rr >> 3) & 3, jv = rr & 7;
        vt_img[((size_t)(bb2 * 32 + t)) * 4096 + ht * 1024 + jpv * 512 + gv * 128 + cv * 8 + jv] = bf2u((bf16)val);
      }
    }
  }
}

// ---------------------------------------------------------------------------
// Kernel 3: causal flash attention, split-KV, swapped-operand MFMA.
// Wave = 16 q-rows x <=4 KV tiles of 64 (CH=4). Fragment-ordered K/V images:
// every load is a contiguous 1KB wave transaction. Lane-local softmax.
// Band m = qt>>4 has m+1 chunks; waves/batch = 576; grid 1152 blocks.
// ---------------------------------------------------------------------------
struct KF { bf16x8 f[4][2]; };

__device__ __forceinline__ void load_kf(KF& k, const u16* kbase, int t) {
#pragma unroll
  for (int nt = 0; nt < 4; ++nt)
#pragma unroll
    for (int jp = 0; jp < 2; ++jp)
      k.f[nt][jp] = *(const bf16x8*)(kbase + (size_t)t * 4096 + nt * 1024 + jp * 512);
}

__device__ __forceinline__ void tile_body(int t, const KF& kU, KF& kP, bool doPre,
                                          const u16* kbase, const u16* vbase,
                                          int t0, int nkt, int q0,
                                          const bf16x8& qb0, const bf16x8& qb1,
                                          int c, int g, char* pw,
                                          f32x4 (&accO)[4], float& mrun, float& lrun) {
  // V fragments for this tile (A-operand of PV^T), contiguous loads
  KF v;
#pragma unroll
  for (int ht = 0; ht < 4; ++ht)
#pragma unroll
    for (int jp = 0; jp < 2; ++jp)
      v.f[ht][jp] = *(const bf16x8*)(vbase + (size_t)t * 4096 + ht * 1024 + jp * 512);
  SBAR();
  // S^T[kpos][q] = K . Q^T   (rows = kpos, cols = q = lane&15)
  f32x4 st[4];
#pragma unroll
  for (int nt = 0; nt < 4; ++nt) {
    f32x4 z = (f32x4){0.f, 0.f, 0.f, 0.f};
    z = MFMA16(kU.f[nt][0], qb0, z);
    st[nt] = MFMA16(kU.f[nt][1], qb1, z);
  }
  if (doPre) load_kf(kP, kbase, t + 1);
  SBAR();
  int tt = t0 + t;
  if (tt == nkt - 1) {   // diagonal tile: mask kpos > q
    int qg = q0 + c, kb = tt * 64 + g * 4;
#pragma unroll
    for (int nt = 0; nt < 4; ++nt)
#pragma unroll
      for (int reg = 0; reg < 4; ++reg)
        if (kb + nt * 16 + reg > qg) st[nt][reg] = NEG_INF;
  }
  // lane-local softmax over 16 held kpos + cross-group (xor16, xor32)
  float smax = st[0][0];
#pragma unroll
  for (int nt = 0; nt < 4; ++nt)
#pragma unroll
    for (int reg = 0; reg < 4; ++reg) smax = fmaxf(smax, st[nt][reg]);
  smax = fmaxf(smax, __shfl_xor(smax, 16));
  smax = fmaxf(smax, __shfl_xor(smax, 32));
  float mnew = fmaxf(mrun, smax);
  float sf = exp2f(mrun - mnew);
  float rsum = 0.f;
  u32 pk[4][2];
#pragma unroll
  for (int nt = 0; nt < 4; ++nt)
#pragma unroll
    for (int jp = 0; jp < 2; ++jp) {
      float p0 = exp2f(st[nt][2 * jp] - mnew);
      float p1 = exp2f(st[nt][2 * jp + 1] - mnew);
      rsum += p0 + p1;
      pk[nt][jp] = (u32)bf2u((bf16)p0) | ((u32)bf2u((bf16)p1) << 16);
    }
  rsum += __shfl_xor(rsum, 16);
  rsum += __shfl_xor(rsum, 32);
  lrun = lrun * sf + rsum;
  mrun = mnew;
#pragma unroll
  for (int ht = 0; ht < 4; ++ht) accO[ht] *= sf;
  // P (q-row c, 64 kpos) -> wave-private swizzled LDS row, packed b32 writes
  int swz = (c & 7) << 4;
#pragma unroll
  for (int nt = 0; nt < 4; ++nt)
#pragma unroll
    for (int jp = 0; jp < 2; ++jp) {
      int kpos = nt * 16 + g * 4 + 2 * jp;
      *(u32*)(pw + ((2 * kpos) ^ swz)) = pk[nt][jp];
    }
  // P^T as B-operand: col = q = c, k = kpos (8 consecutive)
  bf16x8 pf0 = *(const bf16x8*)(pw + ((16 * g) ^ swz));
  bf16x8 pf1 = *(const bf16x8*)(pw + ((64 + 16 * g) ^ swz));
#pragma unroll
  for (int ht = 0; ht < 4; ++ht) {
    accO[ht] = MFMA16(v.f[ht][0], pf0, accO[ht]);
    accO[ht] = MFMA16(v.f[ht][1], pf1, accO[ht]);
  }
}

__global__ __launch_bounds__(256) void attn_kernel(const u16* __restrict__ q_ws,
                                                   const u16* __restrict__ k_img,
                                                   const u16* __restrict__ vt_img,
                                                   float* __restrict__ po,
                                                   float* __restrict__ ml,
                                                   float* __restrict__ out) {
  __shared__ __align__(16) char sP[4 * 2048];
  int tid = threadIdx.x, lane = tid & 63, w = tid >> 6;
  int bid = blockIdx.x;
  int b = bid & 7;                       // batch -> XCD
  int u = (bid >> 3) * 4 + w;            // [0, 576)
  int m, lo;
  if (u < 16)       { m = 0; lo = 0; }
  else if (u < 48)  { m = 1; lo = 16; }
  else if (u < 96)  { m = 2; lo = 48; }
  else if (u < 160) { m = 3; lo = 96; }
  else if (u < 240) { m = 4; lo = 160; }
  else if (u < 336) { m = 5; lo = 240; }
  else if (u < 448) { m = 6; lo = 336; }
  else              { m = 7; lo = 448; }
  int local = u - lo;
  int qt = 16 * m + (local & 15);
  int ci = local >> 4;                   // 0..m
  int nkt = (qt >> 2) + 1;
  int t0 = ci * 4;
  int n = nkt - t0; if (n > 4) n = 4;
  int q0 = qt * 16;
  int c = lane & 15, g = lane >> 4;

  // Q as B-operand: col = q = c, k(h) = 8g+j; q pre-scaled by 0.125*log2e
  const u16* qb = q_ws + ((size_t)b * T_ + q0 + c) * 64 + 8 * g;
  bf16x8 qb0 = *(const bf16x8*)qb;
  bf16x8 qb1 = *(const bf16x8*)(qb + 32);

  const u16* kbase = k_img + ((size_t)(b * 32 + t0)) * 4096 + lane * 8;
  const u16* vbase = vt_img + ((size_t)(b * 32 + t0)) * 4096 + lane * 8;

  f32x4 accO[4];
#pragma unroll
  for (int i = 0; i < 4; ++i) accO[i] = (f32x4){0.f, 0.f, 0.f, 0.f};
  float mrun = NEG_INF, lrun = 0.f;
  char* pw = sP + w * 2048 + c * 128;

  KF kA, kB;
  load_kf(kA, kbase, 0);
  /* explicit bodies, named dbuf structs — all register indexing static */
  tile_body(0, kA, kB, n > 1, kbase, vbase, t0, nkt, q0, qb0, qb1, c, g, pw, accO, mrun, lrun);
  if (n > 1) tile_body(1, kB, kA, n > 2, kbase, vbase, t0, nkt, q0, qb0, qb1, c, g, pw, accO, mrun, lrun);
  if (n > 2) tile_body(2, kA, kB, n > 3, kbase, vbase, t0, nkt, q0, qb0, qb1, c, g, pw, accO, mrun, lrun);
  if (n > 3) tile_body(3, kB, kA, false,  kbase, vbase, t0, nkt, q0, qb0, qb1, c, g, pw, accO, mrun, lrun);

  if (u < 16) {
    // single chunk: normalize, write out (accO is out^T: lane holds col q=c)
    float rl = 1.f / lrun;
    float* ob = out + ((size_t)b * T_ + q0 + c) * 64;
#pragma unroll
    for (int ht = 0; ht < 4; ++ht)
#pragma unroll
      for (int reg = 0; reg < 4; ++reg)
        ob[ht * 16 + g * 4 + reg] = accO[ht][reg] * rl;
  } else {
    int slot = b * 576 + u;
    float* pb = po + (size_t)slot * 1024;   // [64 h][16 q] f32
#pragma unroll
    for (int ht = 0; ht < 4; ++ht)
#pragma unroll
      for (int reg = 0; reg < 4; ++reg)
        pb[(ht * 16 + g * 4 + reg) * 16 + c] = accO[ht][reg];
    if (g == 0) {
      float2 v2; v2.x = mrun; v2.y = lrun;
      *(float2*)(ml + (size_t)slot * 32 + c * 2) = v2;
    }
  }
}

// ---------------------------------------------------------------------------
// Kernel 4: merge split-KV partials for qt in [16,128). Block = one (b,qt).
// Grid MUST be 112*8 = 896. Band m = qt>>4, nc = m+1 chunks at stride 16.
// ---------------------------------------------------------------------------
__global__ __launch_bounds__(256) void merge_kernel(const float* __restrict__ po,
                                                    const float* __restrict__ ml,
                                                    float* __restrict__ out) {
  int bid = blockIdx.x;                 // 896 = 112 * 8
  int b = bid & 7, qi = bid >> 3;
  int qt = 16 + qi;                     // [16, 128)
  int m = qt >> 4;                      // 1..7
  int nc = m + 1;
  int sbase = b * 576 + 8 * m * (m + 1) + (qt & 15);
  int q = threadIdx.x & 15, hq = threadIdx.x >> 4;   // hq in [0,16): h0 = hq*4

  float M = NEG_INF;
  for (int ci = 0; ci < nc; ++ci) {
    float mv = ml[(size_t)(sbase + 16 * ci) * 32 + q * 2];
    M = fmaxf(M, mv);
  }
  float L = 0.f;
  f32x4 acc = (f32x4){0.f, 0.f, 0.f, 0.f};
  for (int ci = 0; ci < nc; ++ci) {
    int sl = sbase + 16 * ci;
    float2 mlv = *(const float2*)(ml + (size_t)sl * 32 + q * 2);
    float wgt = exp2f(mlv.x - M);
    L += wgt * mlv.y;
    const float* pb = po + (size_t)sl * 1024 + hq * 64 + q;
    acc[0] += wgt * pb[0];
    acc[1] += wgt * pb[16];
    acc[2] += wgt * pb[32];
    acc[3] += wgt * pb[48];
  }
  float rl = 1.f / L;
  f32x4 res = acc * rl;
  *(f32x4*)(out + ((size_t)b * T_ + (size_t)qt * 16 + q) * 64 + hq * 4) = res;
}

// ---------------------------------------------------------------------------
extern "C" void kernel_launch(void* const* d_in, const int* in_sizes, int n_in,
                              void* d_out, int out_size, void* d_ws, size_t ws_size,
                              hipStream_t stream) {
  const float* x  = (const float*)d_in[0];
  const float* Wk = (const float*)d_in[1];
  const float* Wq = (const float*)d_in[2];
  const float* Wv = (const float*)d_in[3];
  char* ws = (char*)d_ws;
  u16* q_ws   = (u16*)(ws);                //  0MB: [16384][64] bf16 (q * 0.125*log2e)
  u16* k_img  = (u16*)(ws + 2 * MB);       //  2MB: [8][32][4096] u16 tile image
  u16* vt_img = (u16*)(ws + 4 * MB);       //  4MB: [8][32][4096] u16 tile image
  u16* wt_img = (u16*)(ws + 6 * MB);       //  6MB: 590KB swizzled weights
  float* po   = (float*)(ws + 8 * MB);     //  8MB: 4608 slots x [64][16] f32 = 18.9MB
  float* ml   = (float*)(ws + 28 * MB);    // 28MB: 4608 x [16][2] f32 = 590KB
  float* out = (float*)d_out;

  prepw_kernel<<<576, 256, 0, stream>>>(Wq, Wk, Wv, wt_img);
  proj_kernel<<<256, 1024, 0, stream>>>(x, wt_img, q_ws, k_img, vt_img);
  attn_kernel<<<1152, 256, 0, stream>>>(q_ws, k_img, vt_img, po, ml, out);
  merge_kernel<<<896, 256, 0, stream>>>(po, ml, out);
}

// Round 7
// 49.989 us; speedup vs baseline: 1.8370x; 1.0496x over previous
//
#include <hip/hip_runtime.h>
#include <hip/hip_bf16.h>

typedef unsigned short u16;
typedef unsigned int u32;
typedef __bf16 bf16;
typedef bf16 bf16x8 __attribute__((ext_vector_type(8)));
typedef float f32x4 __attribute__((ext_vector_type(4)));

#define B_ 8
#define T_ 2048
#define C_ 768
#define MB 1048576ull
#define SCALE_Q 0.1803368867f   /* 0.125 * log2(e): folds 1/sqrt(64) and exp->exp2 */
#define NEG_INF (-__builtin_inff())

#define AS1 __attribute__((address_space(1)))
#define AS3 __attribute__((address_space(3)))

__device__ __forceinline__ void g2l16(const void* g, void* l) {
  __builtin_amdgcn_global_load_lds((AS1 const void*)g, (AS3 void*)l, 16, 0, 0);
}
__device__ __forceinline__ u16 bf2u(bf16 h) {
  union { bf16 h; u16 u; } x; x.h = h; return x.u;
}
#define MFMA16(A, B, C) __builtin_amdgcn_mfma_f32_16x16x32_bf16((A), (B), (C), 0, 0, 0)
#define SBAR() __builtin_amdgcn_sched_barrier(0)
#define WAITV4() asm volatile("s_waitcnt vmcnt(4)" ::: "memory")
#define WAITV0() asm volatile("s_waitcnt vmcnt(0)" ::: "memory")
#define BARRIER() do { SBAR(); __builtin_amdgcn_s_barrier(); SBAR(); } while (0)

// ---------------------------------------------------------------------------
// Kernel 1: pre-swizzled Wt image: per K-step s (24), rows j=0..191
// (0..63 = Wq cols, 64..127 = Wk, 128..191 = Wv), 128B pitch,
// element (j, kk) at byte (s*192+j)*128 + ((2*kk) ^ ((j&7)<<4)).
// ---------------------------------------------------------------------------
__global__ __launch_bounds__(256) void prepw_kernel(const float* __restrict__ Wq,
                                                    const float* __restrict__ Wk,
                                                    const float* __restrict__ Wv,
                                                    u16* __restrict__ wt_img) {
  int tid = blockIdx.x * 256 + threadIdx.x;        // 3*768*64 = 147456 exactly
  int jj = tid & 63;
  int k  = (tid >> 6) % C_;
  int m  = tid / (64 * C_);
  const float* W = (m == 0) ? Wq : (m == 1 ? Wk : Wv);
  bf16 hv = (bf16)W[k * 64 + jj];
  int s = k >> 5, kk = k & 31, j = m * 64 + jj;
  int byteoff = (s * 192 + j) * 128 + ((2 * kk) ^ ((j & 7) << 4));
  *(u16*)((char*)wt_img + byteoff) = bf2u(hv);
}

// ---------------------------------------------------------------------------
// Kernel 2: projections. Block = 1024 thr (16 waves, 4m x 4n), 64 rows x 192
// cols, K-loop 24x32. 4 LDS buffers, 2-deep prefetch, counted vmcnt(4),
// ONE barrier per step. (UNCHANGED from round 6 — single-variable round.)
// ---------------------------------------------------------------------------
__global__ __launch_bounds__(1024) void proj_kernel(const float* __restrict__ x,
                                                    const u16* __restrict__ wt_img,
                                                    u16* __restrict__ q_ws,
                                                    u16* __restrict__ k_img,
                                                    u16* __restrict__ vt_img) {
  __shared__ __align__(16) char xt[4][8192];
  __shared__ __align__(16) char wt[4][24576];
  int tid = threadIdx.x, lane = tid & 63, w = tid >> 6;
  int wm = w & 3, wn = w >> 2;           // wm: m-tile (16 rows); wn: 48-col band
  int r0 = blockIdx.x * 64;
  int c = lane & 15, g = lane >> 4;

  f32x4 acc[3];
#pragma unroll
  for (int i = 0; i < 3; ++i) acc[i] = (f32x4){0.f, 0.f, 0.f, 0.f};

  int xs = tid - 512;
  int xrow_s = (xs >> 3) & 63, xch = xs & 7;
  const float* srcx = x + (size_t)(r0 + xrow_s) * C_ + ((xch ^ (xrow_s & 7)) * 4);

  auto STAGE = [&](int s, int bs) {
    const char* wsrc = (const char*)wt_img + s * 24576;
    g2l16(wsrc + tid * 16, wt[bs] + tid * 16);
    if (tid < 512) {
      g2l16(wsrc + (1024 + tid) * 16, wt[bs] + (1024 + tid) * 16);
    } else {
      g2l16(srcx + s * 32, xt[bs] + xs * 16);
    }
  };

  STAGE(0, 0);
  STAGE(1, 1);

  int arow = wm * 16 + c;
  int aswz = (arow & 7) << 4;

  for (int s = 0; s < 24; ++s) {
    int cur = s & 3;
    if (s < 22) {
      STAGE(s + 2, (s + 2) & 3);
      asm volatile("s_waitcnt vmcnt(4)" ::: "memory");   // stage(s) landed
    } else if (s == 22) {
      asm volatile("s_waitcnt vmcnt(2)" ::: "memory");
    } else {
      asm volatile("s_waitcnt vmcnt(0)" ::: "memory");
    }
    BARRIER();
    const char* xrowp = xt[cur] + arow * 128;
    f32x4 f0 = *(const f32x4*)(xrowp + (((2 * g) * 16) ^ aswz));
    f32x4 f1 = *(const f32x4*)(xrowp + (((2 * g + 1) * 16) ^ aswz));
    bf16x8 af;
    af[0] = (bf16)f0[0]; af[1] = (bf16)f0[1]; af[2] = (bf16)f0[2]; af[3] = (bf16)f0[3];
    af[4] = (bf16)f1[0]; af[5] = (bf16)f1[1]; af[6] = (bf16)f1[2]; af[7] = (bf16)f1[3];
    const char* bb = wt[cur];
#pragma unroll
    for (int nt = 0; nt < 3; ++nt) {
      int brow = wn * 48 + nt * 16 + c;
      bf16x8 bfr = *(const bf16x8*)(bb + brow * 128 + ((16 * g) ^ ((brow & 7) << 4)));
      acc[nt] = MFMA16(af, bfr, acc[nt]);
    }
  }

  // epilogue: D layout col = lane&15, row = (lane>>4)*4 + reg
#pragma unroll
  for (int nt = 0; nt < 3; ++nt) {
    int gc = wn * 48 + nt * 16;
    int m = gc >> 6;
    int h = (gc & 63) + c;
#pragma unroll
    for (int reg = 0; reg < 4; ++reg) {
      int r = r0 + wm * 16 + g * 4 + reg;   // token index
      float val = acc[nt][reg];
      int bb2 = r >> 11, rr = r & 2047, t = rr >> 6;
      if (m == 0) {
        q_ws[(size_t)r * 64 + h] = bf2u((bf16)(val * SCALE_Q));
      } else if (m == 1) {
        int ntk = (rr >> 4) & 3, ck = rr & 15;
        int jp = h >> 5, gg = (h >> 3) & 3, jj = h & 7;
        k_img[((size_t)(bb2 * 32 + t)) * 4096 + ntk * 1024 + jp * 512 + gg * 128 + ck * 8 + jj] = bf2u((bf16)val);
      } else {
        int ht = h >> 4, cv = h & 15;
        int jpv = (rr >> 5) & 1, gv = (rr >> 3) & 3, jv = rr & 7;
        vt_img[((size_t)(bb2 * 32 + t)) * 4096 + ht * 1024 + jpv * 512 + gv * 128 + cv * 8 + jv] = bf2u((bf16)val);
      }
    }
  }
}

// ---------------------------------------------------------------------------
// Kernel 3: causal flash attention, split-KV, block-cooperative LDS staging.
// Block = 4 waves = q-tiles {4qb..4qb+3} of one 64-row band, SAME KV chunk of
// <=4 tiles. K/V tiles (fragment-image layout, linear) staged once per block
// via g2l16 into double-buffered LDS; all 4 waves read fragments via
// conflict-free contiguous ds_read_b128. L2 traffic /4 vs per-wave loads.
// Slot math identical to round 6 (merge unchanged). 144 blocks/batch.
// ---------------------------------------------------------------------------
__device__ __forceinline__ void tile_body(int tt, const char* kb, const char* vb,
                                          int nkt, int q0,
                                          const bf16x8& qb0, const bf16x8& qb1,
                                          int lane, int c, int g, char* pw,
                                          f32x4 (&accO)[4], float& mrun, float& lrun) {
  int lb = lane * 16;
  // K fragments (B-op rows = kpos) and V fragments (A-op rows = h) from LDS
  bf16x8 kf[4][2], vf[4][2];
#pragma unroll
  for (int nt = 0; nt < 4; ++nt)
#pragma unroll
    for (int jp = 0; jp < 2; ++jp)
      kf[nt][jp] = *(const bf16x8*)(kb + nt * 2048 + jp * 1024 + lb);
#pragma unroll
  for (int ht = 0; ht < 4; ++ht)
#pragma unroll
    for (int jp = 0; jp < 2; ++jp)
      vf[ht][jp] = *(const bf16x8*)(vb + ht * 2048 + jp * 1024 + lb);
  // S^T[kpos][q] = K . Q^T   (rows = kpos, cols = q = lane&15)
  f32x4 st[4];
#pragma unroll
  for (int nt = 0; nt < 4; ++nt) {
    f32x4 z = (f32x4){0.f, 0.f, 0.f, 0.f};
    z = MFMA16(kf[nt][0], qb0, z);
    st[nt] = MFMA16(kf[nt][1], qb1, z);
  }
  if (tt == nkt - 1) {   // diagonal tile: mask kpos > q
    int qg = q0 + c, kb2 = tt * 64 + g * 4;
#pragma unroll
    for (int nt = 0; nt < 4; ++nt)
#pragma unroll
      for (int reg = 0; reg < 4; ++reg)
        if (kb2 + nt * 16 + reg > qg) st[nt][reg] = NEG_INF;
  }
  // lane-local softmax over 16 held kpos + cross-group (xor16, xor32)
  float smax = st[0][0];
#pragma unroll
  for (int nt = 0; nt < 4; ++nt)
#pragma unroll
    for (int reg = 0; reg < 4; ++reg) smax = fmaxf(smax, st[nt][reg]);
  smax = fmaxf(smax, __shfl_xor(smax, 16));
  smax = fmaxf(smax, __shfl_xor(smax, 32));
  float mnew = fmaxf(mrun, smax);
  float sf = exp2f(mrun - mnew);
  float rsum = 0.f;
  u32 pk[4][2];
#pragma unroll
  for (int nt = 0; nt < 4; ++nt)
#pragma unroll
    for (int jp = 0; jp < 2; ++jp) {
      float p0 = exp2f(st[nt][2 * jp] - mnew);
      float p1 = exp2f(st[nt][2 * jp + 1] - mnew);
      rsum += p0 + p1;
      pk[nt][jp] = (u32)bf2u((bf16)p0) | ((u32)bf2u((bf16)p1) << 16);
    }
  rsum += __shfl_xor(rsum, 16);
  rsum += __shfl_xor(rsum, 32);
  lrun = lrun * sf + rsum;
  mrun = mnew;
#pragma unroll
  for (int ht = 0; ht < 4; ++ht) accO[ht] *= sf;
  // P (q-row c, 64 kpos) -> wave-private swizzled LDS row, packed b32 writes
  int swz = (c & 7) << 4;
#pragma unroll
  for (int nt = 0; nt < 4; ++nt)
#pragma unroll
    for (int jp = 0; jp < 2; ++jp) {
      int kpos = nt * 16 + g * 4 + 2 * jp;
      *(u32*)(pw + ((2 * kpos) ^ swz)) = pk[nt][jp];
    }
  // P^T as B-operand: col = q = c, k = kpos (8 consecutive)
  bf16x8 pf0 = *(const bf16x8*)(pw + ((16 * g) ^ swz));
  bf16x8 pf1 = *(const bf16x8*)(pw + ((64 + 16 * g) ^ swz));
#pragma unroll
  for (int ht = 0; ht < 4; ++ht) {
    accO[ht] = MFMA16(vf[ht][0], pf0, accO[ht]);
    accO[ht] = MFMA16(vf[ht][1], pf1, accO[ht]);
  }
}

__global__ __launch_bounds__(256) void attn_kernel(const u16* __restrict__ q_ws,
                                                   const u16* __restrict__ k_img,
                                                   const u16* __restrict__ vt_img,
                                                   float* __restrict__ po,
                                                   float* __restrict__ ml,
                                                   float* __restrict__ out) {
  __shared__ __align__(16) char sK[2][8192];
  __shared__ __align__(16) char sV[2][8192];
  __shared__ __align__(16) char sP[4 * 2048];
  int tid = threadIdx.x, lane = tid & 63, w = tid >> 6;
  int bid = blockIdx.x;
  int b = bid & 7;                       // batch -> XCD
  int v = bid >> 3;                      // [0, 144)
  int p, lo;
  if (v < 4)        { p = 0; lo = 0; }
  else if (v < 12)  { p = 1; lo = 4; }
  else if (v < 24)  { p = 2; lo = 12; }
  else if (v < 40)  { p = 3; lo = 24; }
  else if (v < 60)  { p = 4; lo = 40; }
  else if (v < 84)  { p = 5; lo = 60; }
  else if (v < 112) { p = 6; lo = 84; }
  else              { p = 7; lo = 112; }
  int local = v - lo;
  int qb = 4 * p + (local & 3);          // 64-row band index [0,32)
  int ci = local >> 2;                   // chunk index [0, (qb>>2)]
  int nkt = qb + 1;
  int t0 = 4 * ci;
  int n = nkt - t0; if (n > 4) n = 4;
  int m = qb >> 2;                       // band (matches qt>>4 for all 4 waves)
  int nc = m + 1;
  int qt = 4 * qb + w;
  int q0 = qt * 16;
  int c = lane & 15, g = lane >> 4;

  // Q as B-operand: col = q = c, k(h) = 8g+j; q pre-scaled by 0.125*log2e
  const u16* qb_p = q_ws + ((size_t)b * T_ + q0 + c) * 64 + 8 * g;
  bf16x8 qb0 = *(const bf16x8*)qb_p;
  bf16x8 qb1 = *(const bf16x8*)(qb_p + 32);

  // Cooperative staging of tile t0+t: K and V images are linear; 256 thr x 4
  // chunks of 16B = 16 KB per tile.
  auto STAGE = [&](int t, int bs) {
    const u16* ks = k_img + ((size_t)(b * 32 + t0 + t)) * 4096;
    const u16* vs = vt_img + ((size_t)(b * 32 + t0 + t)) * 4096;
    g2l16(ks + tid * 8,        sK[bs] + tid * 16);
    g2l16(ks + 2048 + tid * 8, sK[bs] + 4096 + tid * 16);
    g2l16(vs + tid * 8,        sV[bs] + tid * 16);
    g2l16(vs + 2048 + tid * 8, sV[bs] + 4096 + tid * 16);
  };

  f32x4 accO[4];
#pragma unroll
  for (int i = 0; i < 4; ++i) accO[i] = (f32x4){0.f, 0.f, 0.f, 0.f};
  float mrun = NEG_INF, lrun = 0.f;
  char* pw = sP + w * 2048 + c * 128;

  STAGE(0, 0);
  if (n > 1) STAGE(1, 1);
  if (n > 1) WAITV4(); else WAITV0();
  BARRIER();                                  // certify stage 0 (all waves)
  tile_body(t0 + 0, sK[0], sV[0], nkt, q0, qb0, qb1, lane, c, g, pw, accO, mrun, lrun);
  if (n > 1) {
    BARRIER();                                // readers of buf0 done
    if (n > 2) STAGE(2, 0);
    if (n > 2) WAITV4(); else WAITV0();
    BARRIER();                                // certify stage 1
    tile_body(t0 + 1, sK[1], sV[1], nkt, q0, qb0, qb1, lane, c, g, pw, accO, mrun, lrun);
  }
  if (n > 2) {
    BARRIER();                                // readers of buf1 done
    if (n > 3) STAGE(3, 1);
    if (n > 3) WAITV4(); else WAITV0();
    BARRIER();                                // certify stage 2
    tile_body(t0 + 2, sK[0], sV[0], nkt, q0, qb0, qb1, lane, c, g, pw, accO, mrun, lrun);
  }
  if (n > 3) {
    WAITV0();                                 // my stage-3 chunks landed
    BARRIER();                                // everyone's landed
    tile_body(t0 + 3, sK[1], sV[1], nkt, q0, qb0, qb1, lane, c, g, pw, accO, mrun, lrun);
  }

  if (nc == 1) {
    // single chunk (qb < 4): normalize, write out (lane holds out col q=c)
    float rl = 1.f / lrun;
    float* ob = out + ((size_t)b * T_ + q0 + c) * 64;
#pragma unroll
    for (int ht = 0; ht < 4; ++ht)
#pragma unroll
      for (int reg = 0; reg < 4; ++reg)
        ob[ht * 16 + g * 4 + reg] = accO[ht][reg] * rl;
  } else {
    int u = 8 * m * (m + 1) + ci * 16 + (qt & 15);
    int slot = b * 576 + u;
    float* pb = po + (size_t)slot * 1024;   // [64 h][16 q] f32
#pragma unroll
    for (int ht = 0; ht < 4; ++ht)
#pragma unroll
      for (int reg = 0; reg < 4; ++reg)
        pb[(ht * 16 + g * 4 + reg) * 16 + c] = accO[ht][reg];
    if (g == 0) {
      float2 v2; v2.x = mrun; v2.y = lrun;
      *(float2*)(ml + (size_t)slot * 32 + c * 2) = v2;
    }
  }
}

// ---------------------------------------------------------------------------
// Kernel 4: merge split-KV partials for qt in [16,128). Block = one (b,qt).
// Grid MUST be 112*8 = 896. Band m = qt>>4, nc = m+1 chunks at stride 16.
// (UNCHANGED from round 6.)
// ---------------------------------------------------------------------------
__global__ __launch_bounds__(256) void merge_kernel(const float* __restrict__ po,
                                                    const float* __restrict__ ml,
                                                    float* __restrict__ out) {
  int bid = blockIdx.x;                 // 896 = 112 * 8
  int b = bid & 7, qi = bid >> 3;
  int qt = 16 + qi;                     // [16, 128)
  int m = qt >> 4;                      // 1..7
  int nc = m + 1;
  int sbase = b * 576 + 8 * m * (m + 1) + (qt & 15);
  int q = threadIdx.x & 15, hq = threadIdx.x >> 4;   // hq in [0,16): h0 = hq*4

  float M = NEG_INF;
  for (int ci = 0; ci < nc; ++ci) {
    float mv = ml[(size_t)(sbase + 16 * ci) * 32 + q * 2];
    M = fmaxf(M, mv);
  }
  float L = 0.f;
  f32x4 acc = (f32x4){0.f, 0.f, 0.f, 0.f};
  for (int ci = 0; ci < nc; ++ci) {
    int sl = sbase + 16 * ci;
    float2 mlv = *(const float2*)(ml + (size_t)sl * 32 + q * 2);
    float wgt = exp2f(mlv.x - M);
    L += wgt * mlv.y;
    const float* pb = po + (size_t)sl * 1024 + hq * 64 + q;
    acc[0] += wgt * pb[0];
    acc[1] += wgt * pb[16];
    acc[2] += wgt * pb[32];
    acc[3] += wgt * pb[48];
  }
  float rl = 1.f / L;
  f32x4 res = acc * rl;
  *(f32x4*)(out + ((size_t)b * T_ + (size_t)qt * 16 + q) * 64 + hq * 4) = res;
}

// ---------------------------------------------------------------------------
extern "C" void kernel_launch(void* const* d_in, const int* in_sizes, int n_in,
                              void* d_out, int out_size, void* d_ws, size_t ws_size,
                              hipStream_t stream) {
  const float* x  = (const float*)d_in[0];
  const float* Wk = (const float*)d_in[1];
  const float* Wq = (const float*)d_in[2];
  const float* Wv = (const float*)d_in[3];
  char* ws = (char*)d_ws;
  u16* q_ws   = (u16*)(ws);                //  0MB: [16384][64] bf16 (q * 0.125*log2e)
  u16* k_img  = (u16*)(ws + 2 * MB);       //  2MB: [8][32][4096] u16 tile image
  u16* vt_img = (u16*)(ws + 4 * MB);       //  4MB: [8][32][4096] u16 tile image
  u16* wt_img = (u16*)(ws + 6 * MB);       //  6MB: 590KB swizzled weights
  float* po   = (float*)(ws + 8 * MB);     //  8MB: 4608 slots x [64][16] f32 = 18.9MB
  float* ml   = (float*)(ws + 28 * MB);    // 28MB: 4608 x [16][2] f32 = 590KB
  float* out = (float*)d_out;

  prepw_kernel<<<576, 256, 0, stream>>>(Wq, Wk, Wv, wt_img);
  proj_kernel<<<256, 1024, 0, stream>>>(x, wt_img, q_ws, k_img, vt_img);
  attn_kernel<<<1152, 256, 0, stream>>>(q_ws, k_img, vt_img, po, ml, out);
  merge_kernel<<<896, 256, 0, stream>>>(po, ml, out);
}